// Round 5
// baseline (552.268 us; speedup 1.0000x reference)
//
#include <hip/hip_runtime.h>
#include <hip/hip_bf16.h>
#include <math.h>

// CHRONOS inference. Round 5: split-K (head-pair) GAT3 GEMM with f32 atomic
// partials (2504 blocks vs 626 -> fixes 22% occupancy latency wall), 64x64
// tiles for all N=256 GEMMs, multi-dst blocks for the 1-wave kernels.

#define HID 256
#define HEADS 8
#define FIN 235

typedef __attribute__((ext_vector_type(8))) short short8;
typedef __attribute__((ext_vector_type(4))) float floatx4;

__device__ __forceinline__ float elu_f(float x) { return x > 0.f ? x : expm1f(x); }
__device__ __forceinline__ float bf2f(unsigned short u) {
  return __uint_as_float(((unsigned int)u) << 16);
}
__device__ __forceinline__ unsigned short f2bfu(float f) {
  union { __hip_bfloat16 b; unsigned short u; } c;
  c.b = __float2bfloat16(f);
  return c.u;
}

// ---------------- conversions ----------------
__global__ void xcvt_k(const float* __restrict__ x, __hip_bfloat16* __restrict__ xb, int M) {
  int id = blockIdx.x * blockDim.x + threadIdx.x;
  if (id >= M * 256) return;
  int m = id >> 8, k = id & 255;
  xb[id] = (k < FIN) ? __float2bfloat16(x[(size_t)m * FIN + k]) : __float2bfloat16(0.f);
}

__global__ void tcvt_k(const float* __restrict__ w, __hip_bfloat16* __restrict__ wt,
                       int K, int Kpad, int Nstride) {
  __shared__ float t[32][33];
  int nb = blockIdx.x * 32, kb = blockIdx.y * 32;
  int tx = threadIdx.x, ty = threadIdx.y;
#pragma unroll
  for (int j = 0; j < 32; j += 8) {
    int k = kb + ty + j;
    t[ty + j][tx] = (k < K) ? w[(size_t)k * Nstride + nb + tx] : 0.f;
  }
  __syncthreads();
#pragma unroll
  for (int j = 0; j < 32; j += 8) {
    int n = nb + ty + j;
    int k = kb + tx;
    wt[(size_t)n * Kpad + k] = __float2bfloat16(t[tx][ty + j]);
  }
}

// ---------------- CSR build ----------------
__global__ void init_deg_k(int* __restrict__ deg, int* __restrict__ fillc, int n) {
  int i = blockIdx.x * blockDim.x + threadIdx.x;
  if (i < n) { deg[i] = 1; fillc[i] = 0; }
}

__global__ void count_k(const int* __restrict__ ei, int* __restrict__ deg, int E) {
  int i = blockIdx.x * blockDim.x + threadIdx.x;
  if (i < E) atomicAdd(&deg[ei[E + i]], 1);
}

__global__ void scan_k(const int* __restrict__ deg, int* __restrict__ rp, int n) {
  __shared__ int wsum[16];
  __shared__ int s_carry;
  int tid = threadIdx.x, lane = tid & 63, wid = tid >> 6;
  if (tid == 0) { s_carry = 0; rp[0] = 0; }
  __syncthreads();
  for (int base = 0; base < n; base += 1024) {
    int i = base + tid;
    int x = (i < n) ? deg[i] : 0;
#pragma unroll
    for (int off = 1; off < 64; off <<= 1) {
      int y = __shfl_up(x, off);
      if (lane >= off) x += y;
    }
    if (lane == 63) wsum[wid] = x;
    __syncthreads();
    if (wid == 0 && lane < 16) {
      int s = wsum[lane];
#pragma unroll
      for (int off = 1; off < 16; off <<= 1) {
        int y = __shfl_up(s, off);
        if (lane >= off) s += y;
      }
      wsum[lane] = s;
    }
    __syncthreads();
    int offset = s_carry + (wid > 0 ? wsum[wid - 1] : 0);
    if (i < n) rp[i + 1] = offset + x;
    __syncthreads();
    if (tid == 1023) s_carry += wsum[15];
    __syncthreads();
  }
}

__global__ void fill_k(const int* __restrict__ ei, const int* __restrict__ rp,
                       int* __restrict__ fillc, int* __restrict__ colA, int E, int n) {
  int i = blockIdx.x * blockDim.x + threadIdx.x;
  if (i < E) {
    int d = ei[E + i];
    int pos = rp[d] + atomicAdd(&fillc[d], 1);
    colA[pos] = ei[i];
  } else if (i < E + n) {
    int v = i - E;
    int pos = rp[v] + atomicAdd(&fillc[v], 1);
    colA[pos] = v;
  }
}

// ---------------- bf16 MFMA GEMM, TILE 64x64, BK=32 ----------------
// 4 waves in 2x2; each wave 32x32 via 2x2 mfma_16x16x32 frags.
template <int ACT, int BF16OUT>
__global__ __launch_bounds__(256) void mgemm64_k(
    const __hip_bfloat16* __restrict__ A, const __hip_bfloat16* __restrict__ Bt,
    const float* __restrict__ bias, float* __restrict__ Cf,
    __hip_bfloat16* __restrict__ Cb, int ldc, int M, int N, int K) {
  __shared__ short As[64 * 40];
  __shared__ short Bs[64 * 40];
  int tid = threadIdx.x;
  int row0 = blockIdx.y * 64, col0 = blockIdx.x * 64;
  int w = tid >> 6, lane = tid & 63;
  int wr = w >> 1, wc = w & 1;
  int quad = lane >> 4, l16 = lane & 15;
  floatx4 zero = {0.f, 0.f, 0.f, 0.f};
  floatx4 acc[2][2];
#pragma unroll
  for (int i = 0; i < 2; i++)
#pragma unroll
    for (int j = 0; j < 2; j++) acc[i][j] = zero;

  int srow = tid >> 2, sq = tid & 3;
  const __hip_bfloat16* Ap = A + (size_t)(row0 + srow) * K + sq * 8;
  const __hip_bfloat16* Bp = Bt + (size_t)(col0 + srow) * K + sq * 8;
  bool aok = (row0 + srow) < M;

  uint4 a1 = make_uint4(0, 0, 0, 0);
  if (aok) a1 = *(const uint4*)(Ap);
  uint4 b1 = *(const uint4*)(Bp);

  for (int k0 = 0; k0 < K; k0 += 32) {
    __syncthreads();
    *(uint4*)&As[srow * 40 + sq * 8] = a1;
    *(uint4*)&Bs[srow * 40 + sq * 8] = b1;
    int kn = k0 + 32;
    if (kn < K) {
      if (aok) a1 = *(const uint4*)(Ap + kn);
      b1 = *(const uint4*)(Bp + kn);
    }
    __syncthreads();
    short8 fa[2], fb[2];
#pragma unroll
    for (int i = 0; i < 2; i++) {
      fa[i] = *(const short8*)&As[(wr * 32 + i * 16 + l16) * 40 + quad * 8];
      fb[i] = *(const short8*)&Bs[(wc * 32 + i * 16 + l16) * 40 + quad * 8];
    }
#pragma unroll
    for (int mi = 0; mi < 2; mi++)
#pragma unroll
      for (int ni = 0; ni < 2; ni++)
        acc[mi][ni] = __builtin_amdgcn_mfma_f32_16x16x32_bf16(fa[mi], fb[ni], acc[mi][ni], 0, 0, 0);
  }

#pragma unroll
  for (int mi = 0; mi < 2; mi++) {
    int rbase = row0 + wr * 32 + mi * 16 + quad * 4;
#pragma unroll
    for (int ni = 0; ni < 2; ni++) {
      int c = col0 + wc * 32 + ni * 16 + l16;
      float bv = bias ? bias[c] : 0.f;
#pragma unroll
      for (int reg = 0; reg < 4; reg++) {
        int rr = rbase + reg;
        if (rr >= M) continue;
        float v = acc[mi][ni][reg] + bv;
        if (ACT == 1) v = fmaxf(v, 0.f);
        if (ACT == 2) v = elu_f(v);
        if (BF16OUT) Cb[(size_t)rr * ldc + c] = __float2bfloat16(v);
        else Cf[(size_t)rr * ldc + c] = v;
      }
    }
  }
}

// ---------------- dual GEMM (N=512): A@[w_t1 | w_g1], split epilogue ----------------
__global__ __launch_bounds__(256) void mgemm_dual_k(
    const __hip_bfloat16* __restrict__ A, const __hip_bfloat16* __restrict__ Bt,
    const float* __restrict__ bias1, __hip_bfloat16* __restrict__ O1,
    __hip_bfloat16* __restrict__ O2, int M) {
  const int K = 256;
  __shared__ short As[64 * 40];
  __shared__ short Bs[128 * 40];
  int tid = threadIdx.x;
  int row0 = blockIdx.y * 64, col0 = blockIdx.x * 128;
  int w = tid >> 6, lane = tid & 63;
  int wr = w >> 1, wc = w & 1;
  int quad = lane >> 4, l16 = lane & 15;
  floatx4 zero = {0.f, 0.f, 0.f, 0.f};
  floatx4 acc[2][4];
#pragma unroll
  for (int i = 0; i < 2; i++)
#pragma unroll
    for (int j = 0; j < 4; j++) acc[i][j] = zero;

  int srow = tid >> 2, sq = tid & 3;
  const __hip_bfloat16* Ap = A + (size_t)(row0 + srow) * K + sq * 8;
  const __hip_bfloat16* Bp1 = Bt + (size_t)(col0 + srow) * K + sq * 8;
  const __hip_bfloat16* Bp2 = Bt + (size_t)(col0 + 64 + srow) * K + sq * 8;
  bool aok = (row0 + srow) < M;

  uint4 a1 = make_uint4(0, 0, 0, 0);
  if (aok) a1 = *(const uint4*)(Ap);
  uint4 b1 = *(const uint4*)(Bp1);
  uint4 b2 = *(const uint4*)(Bp2);

  for (int k0 = 0; k0 < K; k0 += 32) {
    __syncthreads();
    *(uint4*)&As[srow * 40 + sq * 8] = a1;
    *(uint4*)&Bs[srow * 40 + sq * 8] = b1;
    *(uint4*)&Bs[(64 + srow) * 40 + sq * 8] = b2;
    int kn = k0 + 32;
    if (kn < K) {
      if (aok) a1 = *(const uint4*)(Ap + kn);
      b1 = *(const uint4*)(Bp1 + kn);
      b2 = *(const uint4*)(Bp2 + kn);
    }
    __syncthreads();
    short8 fa[2], fb[4];
#pragma unroll
    for (int i = 0; i < 2; i++)
      fa[i] = *(const short8*)&As[(wr * 32 + i * 16 + l16) * 40 + quad * 8];
#pragma unroll
    for (int i = 0; i < 4; i++)
      fb[i] = *(const short8*)&Bs[(wc * 64 + i * 16 + l16) * 40 + quad * 8];
#pragma unroll
    for (int mi = 0; mi < 2; mi++)
#pragma unroll
      for (int ni = 0; ni < 4; ni++)
        acc[mi][ni] = __builtin_amdgcn_mfma_f32_16x16x32_bf16(fa[mi], fb[ni], acc[mi][ni], 0, 0, 0);
  }

#pragma unroll
  for (int mi = 0; mi < 2; mi++) {
    int rbase = row0 + wr * 32 + mi * 16 + quad * 4;
#pragma unroll
    for (int ni = 0; ni < 4; ni++) {
      int c = col0 + wc * 64 + ni * 16 + l16;
      bool first = c < 256;
      float bv = first ? bias1[c] : 0.f;
      int cc = first ? c : (c - 256);
#pragma unroll
      for (int reg = 0; reg < 4; reg++) {
        int rr = rbase + reg;
        if (rr >= M) continue;
        float v = acc[mi][ni][reg] + bv;
        if (first) v = fmaxf(v, 0.f);
        __hip_bfloat16* dst = first ? O1 : O2;
        dst[(size_t)rr * 256 + cc] = __float2bfloat16(v);
      }
    }
  }
}

// ---------------- split-K GAT3 GEMM: z = head-pair; atomic f32 partials ----------------
// A [M,2048] (k = h*256+c), Bt [256,2048]. Block handles heads {2z, 2z+1}
// (K-slice of 512), folds 0.125*elu(acc + b_h) and atomicAdds into combf[M,256].
__global__ __launch_bounds__(256) void mgemm3s_k(
    const __hip_bfloat16* __restrict__ A, const __hip_bfloat16* __restrict__ Bt,
    const float* __restrict__ bias, float* __restrict__ combf, int M) {
  const int K = 2048;
  __shared__ short As[64 * 40];
  __shared__ short Bs[128 * 40];
  int tid = threadIdx.x;
  int row0 = blockIdx.y * 64, col0 = blockIdx.x * 128;
  int kbeg = blockIdx.z * 512, kend = kbeg + 512;
  int w = tid >> 6, lane = tid & 63;
  int wr = w >> 1, wc = w & 1;
  int quad = lane >> 4, l16 = lane & 15;
  floatx4 zero = {0.f, 0.f, 0.f, 0.f};
  floatx4 acc[2][4], sum[2][4];
#pragma unroll
  for (int i = 0; i < 2; i++)
#pragma unroll
    for (int j = 0; j < 4; j++) { acc[i][j] = zero; sum[i][j] = zero; }

  int srow = tid >> 2, sq = tid & 3;
  const __hip_bfloat16* Ap = A + (size_t)(row0 + srow) * K + sq * 8;
  const __hip_bfloat16* Bp1 = Bt + (size_t)(col0 + srow) * K + sq * 8;
  const __hip_bfloat16* Bp2 = Bt + (size_t)(col0 + 64 + srow) * K + sq * 8;
  bool aok = (row0 + srow) < M;

  uint4 a1 = make_uint4(0, 0, 0, 0);
  if (aok) a1 = *(const uint4*)(Ap + kbeg);
  uint4 b1 = *(const uint4*)(Bp1 + kbeg);
  uint4 b2 = *(const uint4*)(Bp2 + kbeg);

  for (int k0 = kbeg; k0 < kend; k0 += 32) {
    __syncthreads();
    *(uint4*)&As[srow * 40 + sq * 8] = a1;
    *(uint4*)&Bs[srow * 40 + sq * 8] = b1;
    *(uint4*)&Bs[(64 + srow) * 40 + sq * 8] = b2;
    int kn = k0 + 32;
    if (kn < kend) {
      if (aok) a1 = *(const uint4*)(Ap + kn);
      b1 = *(const uint4*)(Bp1 + kn);
      b2 = *(const uint4*)(Bp2 + kn);
    }
    __syncthreads();
    short8 fa[2], fb[4];
#pragma unroll
    for (int i = 0; i < 2; i++)
      fa[i] = *(const short8*)&As[(wr * 32 + i * 16 + l16) * 40 + quad * 8];
#pragma unroll
    for (int i = 0; i < 4; i++)
      fb[i] = *(const short8*)&Bs[(wc * 64 + i * 16 + l16) * 40 + quad * 8];
#pragma unroll
    for (int mi = 0; mi < 2; mi++)
#pragma unroll
      for (int ni = 0; ni < 4; ni++)
        acc[mi][ni] = __builtin_amdgcn_mfma_f32_16x16x32_bf16(fa[mi], fb[ni], acc[mi][ni], 0, 0, 0);
    if (((k0 + 32) & 255) == 0) {  // head boundary
      int h = k0 >> 8;
#pragma unroll
      for (int mi = 0; mi < 2; mi++)
#pragma unroll
        for (int ni = 0; ni < 4; ni++) {
          int c = col0 + wc * 64 + ni * 16 + l16;
          float bv = bias[h * 256 + c];
#pragma unroll
          for (int reg = 0; reg < 4; reg++) {
            sum[mi][ni][reg] += elu_f(acc[mi][ni][reg] + bv);
            acc[mi][ni][reg] = 0.f;
          }
        }
    }
  }

#pragma unroll
  for (int mi = 0; mi < 2; mi++) {
    int rbase = row0 + wr * 32 + mi * 16 + quad * 4;
#pragma unroll
    for (int ni = 0; ni < 4; ni++) {
      int c = col0 + wc * 64 + ni * 16 + l16;
#pragma unroll
      for (int reg = 0; reg < 4; reg++) {
        int rr = rbase + reg;
        if (rr >= M) continue;
        atomicAdd(&combf[(size_t)rr * 256 + c], sum[mi][ni][reg] * 0.125f);
      }
    }
  }
}

// combf f32 [M,256] -> comb[:,0:256] bf16 (stride 512)
__global__ void gfin_k(const float* __restrict__ combf, __hip_bfloat16* __restrict__ comb,
                       int M) {
  int id = blockIdx.x * blockDim.x + threadIdx.x;
  if (id >= M * 256) return;
  comb[(size_t)(id >> 8) * 512 + (id & 255)] = __float2bfloat16(combf[id]);
}

// ---------------- attention-vector projection for GAT3 ----------------
__global__ void aproj_k(const float* __restrict__ w_g3, const float* __restrict__ a_s,
                        const float* __restrict__ a_d, float* __restrict__ apj) {
  int idx = blockIdx.x * blockDim.x + threadIdx.x;
  if (idx >= 256 * 16) return;
  int k = idx >> 4, o = idx & 15;
  int h = o >> 1;
  const float* av = (o & 1) ? (a_d + h * 256) : (a_s + h * 256);
  const float* wr = w_g3 + (size_t)k * 2048 + h * 256;
  float s = 0.f;
  for (int c = 0; c < 256; c++) s += wr[c] * av[c];
  apj[idx] = s;
}

__global__ __launch_bounds__(256) void alpha3_k(const __hip_bfloat16* __restrict__ g2,
                                                const float* __restrict__ apj,
                                                float* __restrict__ as_, float* __restrict__ ad_,
                                                int M) {
  int tid = threadIdx.x;
  int nl = tid >> 4, o = tid & 15;
  int n = blockIdx.x * 16 + nl;
  if (n >= M) return;
  const __hip_bfloat16* row = g2 + (size_t)n * 256;
  float s = 0.f;
  for (int c = 0; c < 256; c++) s += __bfloat162float(row[c]) * apj[c * 16 + o];
  if (o & 1) ad_[n * 8 + (o >> 1)] = s;
  else as_[n * 8 + (o >> 1)] = s;
}

__global__ void alpha_small_k(const __hip_bfloat16* __restrict__ hW, const float* __restrict__ a_s,
                              const float* __restrict__ a_d, float* __restrict__ as_,
                              float* __restrict__ ad_, int M) {
  int idx = blockIdx.x * blockDim.x + threadIdx.x;
  if (idx >= M * HEADS) return;
  int h = idx & 7;
  const __hip_bfloat16* row = hW + (size_t)(idx >> 3) * HID + h * 32;
  const float* ws = a_s + h * 32;
  const float* wd = a_d + h * 32;
  float s = 0.f, d = 0.f;
#pragma unroll
  for (int c = 0; c < 32; c++) {
    float v = __bfloat162float(row[c]);
    s += v * ws[c];
    d += v * wd[c];
  }
  as_[idx] = s;
  ad_[idx] = d;
}

// ---------------- edge softmax: unnormalized ex + invden ----------------
__global__ __launch_bounds__(256) void esoft_k(const int* __restrict__ rp,
                                               const int* __restrict__ col,
                                               const float* __restrict__ as_,
                                               const float* __restrict__ ad_,
                                               float* __restrict__ ex,
                                               float* __restrict__ invden, int M) {
  int dst = blockIdx.x * 4 + (threadIdx.x >> 6);
  if (dst >= M) return;
  int lane = threadIdx.x & 63;
  int es = lane >> 3, h = lane & 7;
  int beg = rp[dst], end = rp[dst + 1];
  float adv = ad_[dst * 8 + h];
  float m = -3.4e38f;
  for (int i = beg + es; i < end; i += 8) {
    float e = as_[col[i] * 8 + h] + adv;
    e = e > 0.f ? e : 0.2f * e;
    m = fmaxf(m, e);
  }
  m = fmaxf(m, __shfl_xor(m, 8));
  m = fmaxf(m, __shfl_xor(m, 16));
  m = fmaxf(m, __shfl_xor(m, 32));
  float den = 0.f;
  for (int i = beg + es; i < end; i += 8) {
    float e = as_[col[i] * 8 + h] + adv;
    e = e > 0.f ? e : 0.2f * e;
    float v = __expf(e - m);
    ex[(size_t)i * 8 + h] = v;
    den += v;
  }
  den += __shfl_xor(den, 8);
  den += __shfl_xor(den, 16);
  den += __shfl_xor(den, 32);
  if (es == 0) invden[dst * 8 + h] = 1.f / (den + 1e-16f);
}

// ---------------- weighted aggregate, GAT1/2 (4 dsts/block) ----------------
__global__ __launch_bounds__(256) void aggw_k(const int* __restrict__ rp,
                                              const int* __restrict__ col,
                                              const __hip_bfloat16* __restrict__ hW,
                                              const float* __restrict__ ex,
                                              const float* __restrict__ invden,
                                              const float* __restrict__ bias,
                                              __hip_bfloat16* __restrict__ out, int M) {
  int dst = blockIdx.x * 4 + (threadIdx.x >> 6);
  if (dst >= M) return;
  int t = threadIdx.x & 63;
  int h = t >> 3, c = t << 2;
  int beg = rp[dst], end = rp[dst + 1];
  float a0 = 0.f, a1 = 0.f, a2 = 0.f, a3 = 0.f;
  for (int i = beg; i < end; i++) {
    int s = col[i];
    float wgt = ex[(size_t)i * 8 + h];
    union { uint2 u; unsigned short us[4]; } uu;
    uu.u = *(const uint2*)(hW + (size_t)s * HID + c);
    a0 += wgt * bf2f(uu.us[0]);
    a1 += wgt * bf2f(uu.us[1]);
    a2 += wgt * bf2f(uu.us[2]);
    a3 += wgt * bf2f(uu.us[3]);
  }
  float inv = invden[dst * 8 + h];
  out[(size_t)dst * HID + c + 0] = __float2bfloat16(elu_f(a0 * inv + bias[c + 0]));
  out[(size_t)dst * HID + c + 1] = __float2bfloat16(elu_f(a1 * inv + bias[c + 1]));
  out[(size_t)dst * HID + c + 2] = __float2bfloat16(elu_f(a2 * inv + bias[c + 2]));
  out[(size_t)dst * HID + c + 3] = __float2bfloat16(elu_f(a3 * inv + bias[c + 3]));
}

// ---------------- GAT3 aggregate (2 dsts/block) ----------------
__global__ __launch_bounds__(256) void agg3_k(const int* __restrict__ rp,
                                              const int* __restrict__ col,
                                              const __hip_bfloat16* __restrict__ g2,
                                              const float* __restrict__ ex,
                                              const float* __restrict__ invden,
                                              __hip_bfloat16* __restrict__ outA, int M) {
  int dst = blockIdx.x * 2 + (threadIdx.x >> 7);
  if (dst >= M) return;
  int t = threadIdx.x & 127;
  int beg = rp[dst], end = rp[dst + 1];
  float acc0[8] = {}, acc1[8] = {};
  for (int i = beg; i < end; i++) {
    int s = col[i];
    float4 w0 = *(const float4*)(ex + (size_t)i * 8);
    float4 w1 = *(const float4*)(ex + (size_t)i * 8 + 4);
    union { unsigned int u; unsigned short us[2]; } uu;
    uu.u = *(const unsigned int*)(g2 + (size_t)s * 256 + t * 2);
    float v0 = bf2f(uu.us[0]), v1 = bf2f(uu.us[1]);
    acc0[0] += w0.x * v0; acc0[1] += w0.y * v0; acc0[2] += w0.z * v0; acc0[3] += w0.w * v0;
    acc0[4] += w1.x * v0; acc0[5] += w1.y * v0; acc0[6] += w1.z * v0; acc0[7] += w1.w * v0;
    acc1[0] += w0.x * v1; acc1[1] += w0.y * v1; acc1[2] += w0.z * v1; acc1[3] += w0.w * v1;
    acc1[4] += w1.x * v1; acc1[5] += w1.y * v1; acc1[6] += w1.z * v1; acc1[7] += w1.w * v1;
  }
#pragma unroll
  for (int h = 0; h < 8; h++) {
    float inv = invden[dst * 8 + h];
    unsigned int pack = (unsigned int)f2bfu(acc0[h] * inv) |
                        ((unsigned int)f2bfu(acc1[h] * inv) << 16);
    *(unsigned int*)(outA + (size_t)dst * 2048 + h * 256 + t * 2) = pack;
  }
}

// ---------------- final: logits (4 nodes/block) ----------------
__global__ __launch_bounds__(256) void final_k(const float* __restrict__ hidden,
                                               const float* __restrict__ w,
                                               const float* __restrict__ b,
                                               float* __restrict__ out, int M) {
  int n = blockIdx.x * 4 + (threadIdx.x >> 6);
  if (n >= M) return;
  int l = threadIdx.x & 63;
  const float* hr = hidden + (size_t)n * HID;
  float a0 = 0.f, a1 = 0.f;
  for (int k = l; k < HID; k += 64) {
    float hv = hr[k];
    a0 += hv * w[k * 2 + 0];
    a1 += hv * w[k * 2 + 1];
  }
  for (int off = 32; off > 0; off >>= 1) {
    a0 += __shfl_down(a0, off);
    a1 += __shfl_down(a1, off);
  }
  if (l == 0) {
    out[n * 2 + 0] = a0 + b[0];
    out[n * 2 + 1] = a1 + b[1];
  }
}

extern "C" void kernel_launch(void* const* d_in, const int* in_sizes, int n_in,
                              void* d_out, int out_size, void* d_ws, size_t ws_size,
                              hipStream_t stream) {
  const float* x      = (const float*)d_in[0];
  const int*   ei     = (const int*)d_in[1];
  const float* w_in   = (const float*)d_in[2];
  const float* b_in   = (const float*)d_in[3];
  const float* w_t1   = (const float*)d_in[4];
  const float* b_t1   = (const float*)d_in[5];
  const float* w_t2   = (const float*)d_in[6];
  const float* b_t2   = (const float*)d_in[7];
  const float* w_g1   = (const float*)d_in[8];
  const float* a_src1 = (const float*)d_in[9];
  const float* a_dst1 = (const float*)d_in[10];
  const float* b_g1   = (const float*)d_in[11];
  const float* w_g2   = (const float*)d_in[12];
  const float* a_src2 = (const float*)d_in[13];
  const float* a_dst2 = (const float*)d_in[14];
  const float* b_g2   = (const float*)d_in[15];
  const float* w_g3   = (const float*)d_in[16];
  const float* a_src3 = (const float*)d_in[17];
  const float* a_dst3 = (const float*)d_in[18];
  const float* b_g3   = (const float*)d_in[19];
  const float* w_c1   = (const float*)d_in[20];
  const float* b_c1   = (const float*)d_in[21];
  const float* w_c2   = (const float*)d_in[22];
  const float* b_c2   = (const float*)d_in[23];
  const int M = in_sizes[0] / FIN;  // 20000
  const int E = in_sizes[1] / 2;    // 120000
  (void)n_in; (void)out_size; (void)ws_size;

  char* wsb = (char*)d_ws;
  size_t off = 0;
  auto alloc = [&](size_t bytes) {
    void* p = wsb + off;
    off = (off + bytes + 255) & ~(size_t)255;
    return p;
  };
  typedef __hip_bfloat16 bf;
  bf* xb     = (bf*)alloc((size_t)M * 256 * 2);
  bf* wtin   = (bf*)alloc(256 * 256 * 2);
  bf* wtpair = (bf*)alloc(512 * 256 * 2);
  bf* wtt2   = (bf*)alloc(256 * 256 * 2);
  bf* wtg2   = (bf*)alloc(256 * 256 * 2);
  bf* wtg3s  = (bf*)alloc(256 * 2048 * 2);
  bf* wtc1   = (bf*)alloc(256 * 512 * 2);
  bf* actA   = (bf*)alloc((size_t)M * HID * 2);      // h, later g2
  bf* actB   = (bf*)alloc((size_t)M * HID * 2);      // th, later g1
  bf* hW1    = (bf*)alloc((size_t)M * HID * 2);
  bf* comb   = (bf*)alloc((size_t)M * 2 * HID * 2);  // [g | t]
  bf* hWb    = (bf*)alloc((size_t)M * 2048 * 2);     // agg3 out
  float* combf = (float*)alloc((size_t)M * 256 * 4); // f32 partials; later hidden
  float* hidden = combf;
  float* as_ = (float*)alloc((size_t)M * 8 * 4);
  float* ad_ = (float*)alloc((size_t)M * 8 * 4);
  float* apj = (float*)alloc(256 * 16 * 4);
  float* exw = (float*)alloc((size_t)(E + M) * 8 * 4);
  float* ivd = (float*)alloc((size_t)M * 8 * 4);
  int* deg   = (int*)alloc((size_t)M * 4);
  int* fillc = (int*)alloc((size_t)M * 4);
  int* rp    = (int*)alloc((size_t)(M + 1) * 4);
  int* colA  = (int*)alloc((size_t)(E + M) * 4);

  // ---- conversions ----
  xcvt_k<<<(M * 256 + 255) / 256, 256, 0, stream>>>(x, xb, M);
  dim3 tb(32, 8);
  tcvt_k<<<dim3(8, 8), tb, 0, stream>>>(w_in, wtin, FIN, 256, 256);
  tcvt_k<<<dim3(8, 8), tb, 0, stream>>>(w_t1, wtpair, 256, 256, 256);
  tcvt_k<<<dim3(8, 8), tb, 0, stream>>>(w_g1, wtpair + 256 * 256, 256, 256, 256);
  tcvt_k<<<dim3(8, 8), tb, 0, stream>>>(w_t2, wtt2, 256, 256, 256);
  tcvt_k<<<dim3(8, 8), tb, 0, stream>>>(w_g2, wtg2, 256, 256, 256);
  for (int h = 0; h < 8; h++)
    tcvt_k<<<dim3(8, 8), tb, 0, stream>>>(w_g3 + h * 256, wtg3s + h * 256, 256, 2048, 2048);
  tcvt_k<<<dim3(8, 16), tb, 0, stream>>>(w_c1, wtc1, 512, 512, 256);
  aproj_k<<<16, 256, 0, stream>>>(w_g3, a_src3, a_dst3, apj);

  // ---- CSR build ----
  init_deg_k<<<(M + 255) / 256, 256, 0, stream>>>(deg, fillc, M);
  count_k<<<(E + 255) / 256, 256, 0, stream>>>(ei, deg, E);
  scan_k<<<1, 1024, 0, stream>>>(deg, rp, M);
  fill_k<<<(E + M + 255) / 256, 256, 0, stream>>>(ei, rp, fillc, colA, E, M);

  auto gemm64 = [&](const bf* A, const bf* Bt, const float* bias, float* Cf, bf* Cb,
                    int ldc, int m, int n, int k, int act) {
    dim3 g(n / 64, (m + 63) / 64);
    if (Cb) {
      if (act == 0)      mgemm64_k<0, 1><<<g, 256, 0, stream>>>(A, Bt, bias, nullptr, Cb, ldc, m, n, k);
      else if (act == 1) mgemm64_k<1, 1><<<g, 256, 0, stream>>>(A, Bt, bias, nullptr, Cb, ldc, m, n, k);
      else               mgemm64_k<2, 1><<<g, 256, 0, stream>>>(A, Bt, bias, nullptr, Cb, ldc, m, n, k);
    } else {
      if (act == 0)      mgemm64_k<0, 0><<<g, 256, 0, stream>>>(A, Bt, bias, Cf, nullptr, ldc, m, n, k);
      else if (act == 1) mgemm64_k<1, 0><<<g, 256, 0, stream>>>(A, Bt, bias, Cf, nullptr, ldc, m, n, k);
      else               mgemm64_k<2, 0><<<g, 256, 0, stream>>>(A, Bt, bias, Cf, nullptr, ldc, m, n, k);
    }
  };
  int eg = (M + 3) / 4;
  int mg = (M + 63) / 64;

  // h = elu(x @ w_in + b_in) -> actA
  gemm64(xb, wtin, b_in, nullptr, actA, HID, M, HID, 256, 2);
  // dual: th=relu(h@w_t1+b_t1) -> actB ; hW1 = h@w_g1
  mgemm_dual_k<<<dim3(4, mg), 256, 0, stream>>>(actA, wtpair, b_t1, actB, hW1, M);
  // t = th @ w_t2 + b_t2 -> comb[:,256:512]
  gemm64(actB, wtt2, b_t2, nullptr, comb + HID, 2 * HID, M, HID, 256, 0);

  // ---- GAT 1 ----
  alpha_small_k<<<(M * 8 + 255) / 256, 256, 0, stream>>>(hW1, a_src1, a_dst1, as_, ad_, M);
  esoft_k<<<eg, 256, 0, stream>>>(rp, colA, as_, ad_, exw, ivd, M);
  aggw_k<<<eg, 256, 0, stream>>>(rp, colA, hW1, exw, ivd, b_g1, actB, M);  // g1

  // ---- GAT 2 ----
  gemm64(actB, wtg2, nullptr, nullptr, hW1, HID, M, HID, 256, 0);
  alpha_small_k<<<(M * 8 + 255) / 256, 256, 0, stream>>>(hW1, a_src2, a_dst2, as_, ad_, M);
  esoft_k<<<eg, 256, 0, stream>>>(rp, colA, as_, ad_, exw, ivd, M);
  aggw_k<<<eg, 256, 0, stream>>>(rp, colA, hW1, exw, ivd, b_g2, actA, M);  // g2

  // ---- GAT 3 ----
  alpha3_k<<<(M + 15) / 16, 256, 0, stream>>>(actA, apj, as_, ad_, M);
  esoft_k<<<eg, 256, 0, stream>>>(rp, colA, as_, ad_, exw, ivd, M);
  agg3_k<<<(M + 1) / 2, 256, 0, stream>>>(rp, colA, actA, exw, ivd, hWb, M);
  hipMemsetAsync(combf, 0, (size_t)M * 256 * 4, stream);
  mgemm3s_k<<<dim3(2, mg, 4), 256, 0, stream>>>(hWb, wtg3s, b_g3, combf, M);
  gfin_k<<<(M * 256 + 255) / 256, 256, 0, stream>>>(combf, comb, M);

  // ---- classifier ----
  gemm64(comb, wtc1, b_c1, hidden, nullptr, HID, M, HID, 512, 1);
  final_k<<<eg, 256, 0, stream>>>(hidden, w_c2, b_c2, (float*)d_out, M);
}

// Round 6
// 446.611 us; speedup vs baseline: 1.2366x; 1.2366x over previous
//
#include <hip/hip_runtime.h>
#include <hip/hip_bf16.h>
#include <math.h>

// CHRONOS inference. Round 6: revert split-K atomics (80MB atomic writes were
// the R5 regression); mgemm3 as 64x64-tile (1252 blocks, latency hiding via
// block parallelism); cheap elu (__expf); tail compression: batched weight
// prep, fused esoft+aggw (GAT1/2), classifier GEMM with fused logit reduction.

#define HID 256
#define HEADS 8
#define FIN 235

typedef __attribute__((ext_vector_type(8))) short short8;
typedef __attribute__((ext_vector_type(4))) float floatx4;

__device__ __forceinline__ float elu_f(float x) { return x > 0.f ? x : __expf(x) - 1.f; }
__device__ __forceinline__ float bf2f(unsigned short u) {
  return __uint_as_float(((unsigned int)u) << 16);
}
__device__ __forceinline__ unsigned short f2bfu(float f) {
  union { __hip_bfloat16 b; unsigned short u; } c;
  c.b = __float2bfloat16(f);
  return c.u;
}

// ---------------- conversions ----------------
__global__ void xcvt_k(const float* __restrict__ x, __hip_bfloat16* __restrict__ xb, int M) {
  int id = blockIdx.x * blockDim.x + threadIdx.x;
  if (id >= M * 256) return;
  int m = id >> 8, k = id & 255;
  xb[id] = (k < FIN) ? __float2bfloat16(x[(size_t)m * FIN + k]) : __float2bfloat16(0.f);
}

// batched weight transpose+cast: wt[n*Kpad + k] = w[k*Nstride + n]
// z: 0=w_in 1=w_t1 2=w_g1 3=w_t2 4=w_g2 5=w_c1 6..13=w_g3 head
__global__ void wprep_k(const float* __restrict__ w_in, const float* __restrict__ w_t1,
                        const float* __restrict__ w_g1, const float* __restrict__ w_t2,
                        const float* __restrict__ w_g2, const float* __restrict__ w_c1,
                        const float* __restrict__ w_g3, __hip_bfloat16* __restrict__ wtin,
                        __hip_bfloat16* __restrict__ wtpair, __hip_bfloat16* __restrict__ wtt2,
                        __hip_bfloat16* __restrict__ wtg2, __hip_bfloat16* __restrict__ wtc1,
                        __hip_bfloat16* __restrict__ wtg3s) {
  __shared__ float t[32][33];
  int z = blockIdx.z;
  const float* src;
  __hip_bfloat16* dst;
  int K, Kpad, Nstride;
  if (z == 5) {
    src = w_c1; dst = wtc1; K = 512; Kpad = 512; Nstride = 256;
  } else {
    if (blockIdx.y >= 8) return;
    switch (z) {
      case 0: src = w_in; dst = wtin; K = FIN; Kpad = 256; Nstride = 256; break;
      case 1: src = w_t1; dst = wtpair; K = 256; Kpad = 256; Nstride = 256; break;
      case 2: src = w_g1; dst = wtpair + 256 * 256; K = 256; Kpad = 256; Nstride = 256; break;
      case 3: src = w_t2; dst = wtt2; K = 256; Kpad = 256; Nstride = 256; break;
      case 4: src = w_g2; dst = wtg2; K = 256; Kpad = 256; Nstride = 256; break;
      default: {
        int h = z - 6;
        src = w_g3 + h * 256; dst = wtg3s + h * 256; K = 256; Kpad = 2048; Nstride = 2048;
      }
    }
  }
  int nb = blockIdx.x * 32, kb = blockIdx.y * 32;
  int tx = threadIdx.x, ty = threadIdx.y;
#pragma unroll
  for (int j = 0; j < 32; j += 8) {
    int k = kb + ty + j;
    t[ty + j][tx] = (k < K) ? src[(size_t)k * Nstride + nb + tx] : 0.f;
  }
  __syncthreads();
#pragma unroll
  for (int j = 0; j < 32; j += 8) {
    int n = nb + ty + j;
    int k = kb + tx;
    dst[(size_t)n * Kpad + k] = __float2bfloat16(t[tx][ty + j]);
  }
}

// ---------------- CSR build ----------------
__global__ void count_k(const int* __restrict__ ei, int* __restrict__ deg, int E) {
  int i = blockIdx.x * blockDim.x + threadIdx.x;
  if (i < E) atomicAdd(&deg[ei[E + i]], 1);
}

// rp[i+1] = prefix_sum(deg[0..i] + 1)  (the +1 is the self-loop)
__global__ void scan_k(const int* __restrict__ deg, int* __restrict__ rp, int n) {
  __shared__ int wsum[16];
  __shared__ int s_carry;
  int tid = threadIdx.x, lane = tid & 63, wid = tid >> 6;
  if (tid == 0) { s_carry = 0; rp[0] = 0; }
  __syncthreads();
  for (int base = 0; base < n; base += 1024) {
    int i = base + tid;
    int x = (i < n) ? (deg[i] + 1) : 0;
#pragma unroll
    for (int off = 1; off < 64; off <<= 1) {
      int y = __shfl_up(x, off);
      if (lane >= off) x += y;
    }
    if (lane == 63) wsum[wid] = x;
    __syncthreads();
    if (wid == 0 && lane < 16) {
      int s = wsum[lane];
#pragma unroll
      for (int off = 1; off < 16; off <<= 1) {
        int y = __shfl_up(s, off);
        if (lane >= off) s += y;
      }
      wsum[lane] = s;
    }
    __syncthreads();
    int offset = s_carry + (wid > 0 ? wsum[wid - 1] : 0);
    if (i < n) rp[i + 1] = offset + x;
    __syncthreads();
    if (tid == 1023) s_carry += wsum[15];
    __syncthreads();
  }
}

__global__ void fill_k(const int* __restrict__ ei, const int* __restrict__ rp,
                       int* __restrict__ fillc, int* __restrict__ colA, int E, int n) {
  int i = blockIdx.x * blockDim.x + threadIdx.x;
  if (i < E) {
    int d = ei[E + i];
    int pos = rp[d] + atomicAdd(&fillc[d], 1);
    colA[pos] = ei[i];
  } else if (i < E + n) {
    int v = i - E;
    int pos = rp[v] + atomicAdd(&fillc[v], 1);
    colA[pos] = v;
  }
}

// ---------------- bf16 MFMA GEMM, TILE 64x64, BK=32 ----------------
template <int ACT>
__global__ __launch_bounds__(256) void mgemm64_k(
    const __hip_bfloat16* __restrict__ A, const __hip_bfloat16* __restrict__ Bt,
    const float* __restrict__ bias, __hip_bfloat16* __restrict__ Cb,
    int ldc, int M, int N, int K) {
  __shared__ short As[64 * 40];
  __shared__ short Bs[64 * 40];
  int tid = threadIdx.x;
  int row0 = blockIdx.y * 64, col0 = blockIdx.x * 64;
  int w = tid >> 6, lane = tid & 63;
  int wr = w >> 1, wc = w & 1;
  int quad = lane >> 4, l16 = lane & 15;
  floatx4 zero = {0.f, 0.f, 0.f, 0.f};
  floatx4 acc[2][2];
#pragma unroll
  for (int i = 0; i < 2; i++)
#pragma unroll
    for (int j = 0; j < 2; j++) acc[i][j] = zero;

  int srow = tid >> 2, sq = tid & 3;
  const __hip_bfloat16* Ap = A + (size_t)(row0 + srow) * K + sq * 8;
  const __hip_bfloat16* Bp = Bt + (size_t)(col0 + srow) * K + sq * 8;
  bool aok = (row0 + srow) < M;

  uint4 a1 = make_uint4(0, 0, 0, 0);
  if (aok) a1 = *(const uint4*)(Ap);
  uint4 b1 = *(const uint4*)(Bp);

  for (int k0 = 0; k0 < K; k0 += 32) {
    __syncthreads();
    *(uint4*)&As[srow * 40 + sq * 8] = a1;
    *(uint4*)&Bs[srow * 40 + sq * 8] = b1;
    int kn = k0 + 32;
    if (kn < K) {
      if (aok) a1 = *(const uint4*)(Ap + kn);
      b1 = *(const uint4*)(Bp + kn);
    }
    __syncthreads();
    short8 fa[2], fb[2];
#pragma unroll
    for (int i = 0; i < 2; i++) {
      fa[i] = *(const short8*)&As[(wr * 32 + i * 16 + l16) * 40 + quad * 8];
      fb[i] = *(const short8*)&Bs[(wc * 32 + i * 16 + l16) * 40 + quad * 8];
    }
#pragma unroll
    for (int mi = 0; mi < 2; mi++)
#pragma unroll
      for (int ni = 0; ni < 2; ni++)
        acc[mi][ni] = __builtin_amdgcn_mfma_f32_16x16x32_bf16(fa[mi], fb[ni], acc[mi][ni], 0, 0, 0);
  }

#pragma unroll
  for (int mi = 0; mi < 2; mi++) {
    int rbase = row0 + wr * 32 + mi * 16 + quad * 4;
#pragma unroll
    for (int ni = 0; ni < 2; ni++) {
      int c = col0 + wc * 32 + ni * 16 + l16;
      float bv = bias ? bias[c] : 0.f;
#pragma unroll
      for (int reg = 0; reg < 4; reg++) {
        int rr = rbase + reg;
        if (rr >= M) continue;
        float v = acc[mi][ni][reg] + bv;
        if (ACT == 1) v = fmaxf(v, 0.f);
        if (ACT == 2) v = elu_f(v);
        Cb[(size_t)rr * ldc + c] = __float2bfloat16(v);
      }
    }
  }
}

// ---------------- dual GEMM (N=512): A@[w_t1 | w_g1], split epilogue ----------------
__global__ __launch_bounds__(256) void mgemm_dual_k(
    const __hip_bfloat16* __restrict__ A, const __hip_bfloat16* __restrict__ Bt,
    const float* __restrict__ bias1, __hip_bfloat16* __restrict__ O1,
    __hip_bfloat16* __restrict__ O2, int M) {
  const int K = 256;
  __shared__ short As[64 * 40];
  __shared__ short Bs[128 * 40];
  int tid = threadIdx.x;
  int row0 = blockIdx.y * 64, col0 = blockIdx.x * 128;
  int w = tid >> 6, lane = tid & 63;
  int wr = w >> 1, wc = w & 1;
  int quad = lane >> 4, l16 = lane & 15;
  floatx4 zero = {0.f, 0.f, 0.f, 0.f};
  floatx4 acc[2][4];
#pragma unroll
  for (int i = 0; i < 2; i++)
#pragma unroll
    for (int j = 0; j < 4; j++) acc[i][j] = zero;

  int srow = tid >> 2, sq = tid & 3;
  const __hip_bfloat16* Ap = A + (size_t)(row0 + srow) * K + sq * 8;
  const __hip_bfloat16* Bp1 = Bt + (size_t)(col0 + srow) * K + sq * 8;
  const __hip_bfloat16* Bp2 = Bt + (size_t)(col0 + 64 + srow) * K + sq * 8;
  bool aok = (row0 + srow) < M;

  uint4 a1 = make_uint4(0, 0, 0, 0);
  if (aok) a1 = *(const uint4*)(Ap);
  uint4 b1 = *(const uint4*)(Bp1);
  uint4 b2 = *(const uint4*)(Bp2);

  for (int k0 = 0; k0 < K; k0 += 32) {
    __syncthreads();
    *(uint4*)&As[srow * 40 + sq * 8] = a1;
    *(uint4*)&Bs[srow * 40 + sq * 8] = b1;
    *(uint4*)&Bs[(64 + srow) * 40 + sq * 8] = b2;
    int kn = k0 + 32;
    if (kn < K) {
      if (aok) a1 = *(const uint4*)(Ap + kn);
      b1 = *(const uint4*)(Bp1 + kn);
      b2 = *(const uint4*)(Bp2 + kn);
    }
    __syncthreads();
    short8 fa[2], fb[4];
#pragma unroll
    for (int i = 0; i < 2; i++)
      fa[i] = *(const short8*)&As[(wr * 32 + i * 16 + l16) * 40 + quad * 8];
#pragma unroll
    for (int i = 0; i < 4; i++)
      fb[i] = *(const short8*)&Bs[(wc * 64 + i * 16 + l16) * 40 + quad * 8];
#pragma unroll
    for (int mi = 0; mi < 2; mi++)
#pragma unroll
      for (int ni = 0; ni < 4; ni++)
        acc[mi][ni] = __builtin_amdgcn_mfma_f32_16x16x32_bf16(fa[mi], fb[ni], acc[mi][ni], 0, 0, 0);
  }

#pragma unroll
  for (int mi = 0; mi < 2; mi++) {
    int rbase = row0 + wr * 32 + mi * 16 + quad * 4;
#pragma unroll
    for (int ni = 0; ni < 4; ni++) {
      int c = col0 + wc * 64 + ni * 16 + l16;
      bool first = c < 256;
      float bv = first ? bias1[c] : 0.f;
      int cc = first ? c : (c - 256);
#pragma unroll
      for (int reg = 0; reg < 4; reg++) {
        int rr = rbase + reg;
        if (rr >= M) continue;
        float v = acc[mi][ni][reg] + bv;
        if (first) v = fmaxf(v, 0.f);
        __hip_bfloat16* dst = first ? O1 : O2;
        dst[(size_t)rr * 256 + cc] = __float2bfloat16(v);
      }
    }
  }
}

// ---------------- GAT3 GEMM: comb[:,0:256] = mean_h elu(agg_h @ W_h + b_h) ----------------
// TILE 64x64, K=2048, fold elu+bias every 256 k. grid (4, ceil(M/64)).
__global__ __launch_bounds__(256) void mgemm3_k(
    const __hip_bfloat16* __restrict__ A, const __hip_bfloat16* __restrict__ Bt,
    const float* __restrict__ bias, __hip_bfloat16* __restrict__ comb, int M) {
  const int K = 2048;
  __shared__ short As[64 * 40];
  __shared__ short Bs[64 * 40];
  int tid = threadIdx.x;
  int row0 = blockIdx.y * 64, col0 = blockIdx.x * 64;
  int w = tid >> 6, lane = tid & 63;
  int wr = w >> 1, wc = w & 1;
  int quad = lane >> 4, l16 = lane & 15;
  floatx4 zero = {0.f, 0.f, 0.f, 0.f};
  floatx4 acc[2][2], sum[2][2];
#pragma unroll
  for (int i = 0; i < 2; i++)
#pragma unroll
    for (int j = 0; j < 2; j++) { acc[i][j] = zero; sum[i][j] = zero; }

  int srow = tid >> 2, sq = tid & 3;
  const __hip_bfloat16* Ap = A + (size_t)(row0 + srow) * K + sq * 8;
  const __hip_bfloat16* Bp = Bt + (size_t)(col0 + srow) * K + sq * 8;
  bool aok = (row0 + srow) < M;

  uint4 a1 = make_uint4(0, 0, 0, 0);
  if (aok) a1 = *(const uint4*)(Ap);
  uint4 b1 = *(const uint4*)(Bp);

  for (int k0 = 0; k0 < K; k0 += 32) {
    __syncthreads();
    *(uint4*)&As[srow * 40 + sq * 8] = a1;
    *(uint4*)&Bs[srow * 40 + sq * 8] = b1;
    int kn = k0 + 32;
    if (kn < K) {
      if (aok) a1 = *(const uint4*)(Ap + kn);
      b1 = *(const uint4*)(Bp + kn);
    }
    __syncthreads();
    short8 fa[2], fb[2];
#pragma unroll
    for (int i = 0; i < 2; i++) {
      fa[i] = *(const short8*)&As[(wr * 32 + i * 16 + l16) * 40 + quad * 8];
      fb[i] = *(const short8*)&Bs[(wc * 32 + i * 16 + l16) * 40 + quad * 8];
    }
#pragma unroll
    for (int mi = 0; mi < 2; mi++)
#pragma unroll
      for (int ni = 0; ni < 2; ni++)
        acc[mi][ni] = __builtin_amdgcn_mfma_f32_16x16x32_bf16(fa[mi], fb[ni], acc[mi][ni], 0, 0, 0);
    if (((k0 + 32) & 255) == 0) {  // head boundary: fold elu(acc + b_h)
      int h = k0 >> 8;
#pragma unroll
      for (int mi = 0; mi < 2; mi++)
#pragma unroll
        for (int ni = 0; ni < 2; ni++) {
          int c = col0 + wc * 32 + ni * 16 + l16;
          float bv = bias[h * 256 + c];
#pragma unroll
          for (int reg = 0; reg < 4; reg++) {
            sum[mi][ni][reg] += elu_f(acc[mi][ni][reg] + bv);
            acc[mi][ni][reg] = 0.f;
          }
        }
    }
  }

#pragma unroll
  for (int mi = 0; mi < 2; mi++) {
    int rbase = row0 + wr * 32 + mi * 16 + quad * 4;
#pragma unroll
    for (int ni = 0; ni < 2; ni++) {
      int c = col0 + wc * 32 + ni * 16 + l16;
#pragma unroll
      for (int reg = 0; reg < 4; reg++) {
        int rr = rbase + reg;
        if (rr >= M) continue;
        comb[(size_t)rr * 512 + c] = __float2bfloat16(sum[mi][ni][reg] * 0.125f);
      }
    }
  }
}

// ---------------- classifier GEMM + fused logit reduction ----------------
// hidden = relu(comb @ w_c1 + b_c1) tile in regs; logits partial = hidden @ w_c2
// reduced in-block, atomicAdd into out (pre-initialized with b_c2).
__global__ __launch_bounds__(256) void mgemm_cls_k(
    const __hip_bfloat16* __restrict__ A, const __hip_bfloat16* __restrict__ Bt,
    const float* __restrict__ bias, const float* __restrict__ w2,
    float* __restrict__ out, int M) {
  const int K = 512;
  __shared__ short As[64 * 40];
  __shared__ short Bs[64 * 40];
  __shared__ float ls[64][2][2];  // [row_local][wave_c][logit]
  int tid = threadIdx.x;
  int row0 = blockIdx.y * 64, col0 = blockIdx.x * 64;
  int w = tid >> 6, lane = tid & 63;
  int wr = w >> 1, wc = w & 1;
  int quad = lane >> 4, l16 = lane & 15;
  floatx4 zero = {0.f, 0.f, 0.f, 0.f};
  floatx4 acc[2][2];
#pragma unroll
  for (int i = 0; i < 2; i++)
#pragma unroll
    for (int j = 0; j < 2; j++) acc[i][j] = zero;

  int srow = tid >> 2, sq = tid & 3;
  const __hip_bfloat16* Ap = A + (size_t)(row0 + srow) * K + sq * 8;
  const __hip_bfloat16* Bp = Bt + (size_t)(col0 + srow) * K + sq * 8;
  bool aok = (row0 + srow) < M;

  uint4 a1 = make_uint4(0, 0, 0, 0);
  if (aok) a1 = *(const uint4*)(Ap);
  uint4 b1 = *(const uint4*)(Bp);

  for (int k0 = 0; k0 < K; k0 += 32) {
    __syncthreads();
    *(uint4*)&As[srow * 40 + sq * 8] = a1;
    *(uint4*)&Bs[srow * 40 + sq * 8] = b1;
    int kn = k0 + 32;
    if (kn < K) {
      if (aok) a1 = *(const uint4*)(Ap + kn);
      b1 = *(const uint4*)(Bp + kn);
    }
    __syncthreads();
    short8 fa[2], fb[2];
#pragma unroll
    for (int i = 0; i < 2; i++) {
      fa[i] = *(const short8*)&As[(wr * 32 + i * 16 + l16) * 40 + quad * 8];
      fb[i] = *(const short8*)&Bs[(wc * 32 + i * 16 + l16) * 40 + quad * 8];
    }
#pragma unroll
    for (int mi = 0; mi < 2; mi++)
#pragma unroll
      for (int ni = 0; ni < 2; ni++)
        acc[mi][ni] = __builtin_amdgcn_mfma_f32_16x16x32_bf16(fa[mi], fb[ni], acc[mi][ni], 0, 0, 0);
  }

  // per-lane logit partials over this lane's cols
  float p[2][4][2];
#pragma unroll
  for (int mi = 0; mi < 2; mi++)
#pragma unroll
    for (int reg = 0; reg < 4; reg++) { p[mi][reg][0] = 0.f; p[mi][reg][1] = 0.f; }
#pragma unroll
  for (int mi = 0; mi < 2; mi++) {
    int rbase = row0 + wr * 32 + mi * 16 + quad * 4;
#pragma unroll
    for (int ni = 0; ni < 2; ni++) {
      int c = col0 + wc * 32 + ni * 16 + l16;
      float bv = bias[c];
      float w20 = w2[c * 2 + 0], w21 = w2[c * 2 + 1];
#pragma unroll
      for (int reg = 0; reg < 4; reg++) {
        if (rbase + reg >= M) continue;
        float v = fmaxf(acc[mi][ni][reg] + bv, 0.f);
        p[mi][reg][0] += v * w20;
        p[mi][reg][1] += v * w21;
      }
    }
  }
  // reduce over 16 l16 lanes
#pragma unroll
  for (int off = 1; off < 16; off <<= 1)
#pragma unroll
    for (int mi = 0; mi < 2; mi++)
#pragma unroll
      for (int reg = 0; reg < 4; reg++) {
        p[mi][reg][0] += __shfl_xor(p[mi][reg][0], off);
        p[mi][reg][1] += __shfl_xor(p[mi][reg][1], off);
      }
  if (l16 == 0) {
#pragma unroll
    for (int mi = 0; mi < 2; mi++)
#pragma unroll
      for (int reg = 0; reg < 4; reg++) {
        int rl = wr * 32 + mi * 16 + quad * 4 + reg;
        ls[rl][wc][0] = p[mi][reg][0];
        ls[rl][wc][1] = p[mi][reg][1];
      }
  }
  __syncthreads();
  if (tid < 64) {
    int r = row0 + tid;
    if (r < M) {
      atomicAdd(&out[r * 2 + 0], ls[tid][0][0] + ls[tid][1][0]);
      atomicAdd(&out[r * 2 + 1], ls[tid][0][1] + ls[tid][1][1]);
    }
  }
}

__global__ void initout_k(const float* __restrict__ b, float* __restrict__ out, int M) {
  int i = blockIdx.x * blockDim.x + threadIdx.x;
  if (i < M * 2) out[i] = b[i & 1];
}

// ---------------- attention-vector projection for GAT3 ----------------
__global__ void aproj_k(const float* __restrict__ w_g3, const float* __restrict__ a_s,
                        const float* __restrict__ a_d, float* __restrict__ apj) {
  int idx = blockIdx.x * blockDim.x + threadIdx.x;
  if (idx >= 256 * 16) return;
  int k = idx >> 4, o = idx & 15;
  int h = o >> 1;
  const float* av = (o & 1) ? (a_d + h * 256) : (a_s + h * 256);
  const float* wr = w_g3 + (size_t)k * 2048 + h * 256;
  float s = 0.f;
  for (int c = 0; c < 256; c++) s += wr[c] * av[c];
  apj[idx] = s;
}

__global__ __launch_bounds__(256) void alpha3_k(const __hip_bfloat16* __restrict__ g2,
                                                const float* __restrict__ apj,
                                                float* __restrict__ as_, float* __restrict__ ad_,
                                                int M) {
  int tid = threadIdx.x;
  int nl = tid >> 4, o = tid & 15;
  int n = blockIdx.x * 16 + nl;
  if (n >= M) return;
  const __hip_bfloat16* row = g2 + (size_t)n * 256;
  float s = 0.f;
  for (int c = 0; c < 256; c++) s += __bfloat162float(row[c]) * apj[c * 16 + o];
  if (o & 1) ad_[n * 8 + (o >> 1)] = s;
  else as_[n * 8 + (o >> 1)] = s;
}

__global__ void alpha_small_k(const __hip_bfloat16* __restrict__ hW, const float* __restrict__ a_s,
                              const float* __restrict__ a_d, float* __restrict__ as_,
                              float* __restrict__ ad_, int M) {
  int idx = blockIdx.x * blockDim.x + threadIdx.x;
  if (idx >= M * HEADS) return;
  int h = idx & 7;
  const __hip_bfloat16* row = hW + (size_t)(idx >> 3) * HID + h * 32;
  const float* ws = a_s + h * 32;
  const float* wd = a_d + h * 32;
  float s = 0.f, d = 0.f;
#pragma unroll
  for (int c = 0; c < 32; c++) {
    float v = __bfloat162float(row[c]);
    s += v * ws[c];
    d += v * wd[c];
  }
  as_[idx] = s;
  ad_[idx] = d;
}

// ---------------- fused edge-softmax + aggregate (GAT1/2), wave per dst ----------------
// lane t: head h=t>>3, channels 4t..4t+3. Two passes: max, then exp+den+acc.
__global__ __launch_bounds__(256) void aggf_k(const int* __restrict__ rp,
                                              const int* __restrict__ col,
                                              const __hip_bfloat16* __restrict__ hW,
                                              const float* __restrict__ as_,
                                              const float* __restrict__ ad_,
                                              const float* __restrict__ bias,
                                              __hip_bfloat16* __restrict__ out, int M) {
  int dst = blockIdx.x * 4 + (threadIdx.x >> 6);
  if (dst >= M) return;
  int t = threadIdx.x & 63;
  int h = t >> 3, c = t << 2;
  int beg = rp[dst], end = rp[dst + 1];
  float adv = ad_[dst * 8 + h];
  float m = -3.4e38f;
  for (int i = beg; i < end; i++) {
    float e = as_[col[i] * 8 + h] + adv;
    e = e > 0.f ? e : 0.2f * e;
    m = fmaxf(m, e);
  }
  float den = 0.f;
  float a0 = 0.f, a1 = 0.f, a2 = 0.f, a3 = 0.f;
  for (int i = beg; i < end; i++) {
    int s = col[i];
    float e = as_[s * 8 + h] + adv;
    e = e > 0.f ? e : 0.2f * e;
    float ex = __expf(e - m);
    den += ex;
    union { uint2 u; unsigned short us[4]; } uu;
    uu.u = *(const uint2*)(hW + (size_t)s * HID + c);
    a0 += ex * bf2f(uu.us[0]);
    a1 += ex * bf2f(uu.us[1]);
    a2 += ex * bf2f(uu.us[2]);
    a3 += ex * bf2f(uu.us[3]);
  }
  float inv = 1.f / (den + 1e-16f);
  out[(size_t)dst * HID + c + 0] = __float2bfloat16(elu_f(a0 * inv + bias[c + 0]));
  out[(size_t)dst * HID + c + 1] = __float2bfloat16(elu_f(a1 * inv + bias[c + 1]));
  out[(size_t)dst * HID + c + 2] = __float2bfloat16(elu_f(a2 * inv + bias[c + 2]));
  out[(size_t)dst * HID + c + 3] = __float2bfloat16(elu_f(a3 * inv + bias[c + 3]));
}

// ---------------- edge softmax (GAT3 only) ----------------
__global__ __launch_bounds__(256) void esoft_k(const int* __restrict__ rp,
                                               const int* __restrict__ col,
                                               const float* __restrict__ as_,
                                               const float* __restrict__ ad_,
                                               float* __restrict__ ex,
                                               float* __restrict__ invden, int M) {
  int dst = blockIdx.x * 4 + (threadIdx.x >> 6);
  if (dst >= M) return;
  int lane = threadIdx.x & 63;
  int es = lane >> 3, h = lane & 7;
  int beg = rp[dst], end = rp[dst + 1];
  float adv = ad_[dst * 8 + h];
  float m = -3.4e38f;
  for (int i = beg + es; i < end; i += 8) {
    float e = as_[col[i] * 8 + h] + adv;
    e = e > 0.f ? e : 0.2f * e;
    m = fmaxf(m, e);
  }
  m = fmaxf(m, __shfl_xor(m, 8));
  m = fmaxf(m, __shfl_xor(m, 16));
  m = fmaxf(m, __shfl_xor(m, 32));
  float den = 0.f;
  for (int i = beg + es; i < end; i += 8) {
    float e = as_[col[i] * 8 + h] + adv;
    e = e > 0.f ? e : 0.2f * e;
    float v = __expf(e - m);
    ex[(size_t)i * 8 + h] = v;
    den += v;
  }
  den += __shfl_xor(den, 8);
  den += __shfl_xor(den, 16);
  den += __shfl_xor(den, 32);
  if (es == 0) invden[dst * 8 + h] = 1.f / (den + 1e-16f);
}

// ---------------- GAT3 aggregate (2 dsts/block) ----------------
__global__ __launch_bounds__(256) void agg3_k(const int* __restrict__ rp,
                                              const int* __restrict__ col,
                                              const __hip_bfloat16* __restrict__ g2,
                                              const float* __restrict__ ex,
                                              const float* __restrict__ invden,
                                              __hip_bfloat16* __restrict__ outA, int M) {
  int dst = blockIdx.x * 2 + (threadIdx.x >> 7);
  if (dst >= M) return;
  int t = threadIdx.x & 127;
  int beg = rp[dst], end = rp[dst + 1];
  float acc0[8] = {}, acc1[8] = {};
  for (int i = beg; i < end; i++) {
    int s = col[i];
    float4 w0 = *(const float4*)(ex + (size_t)i * 8);
    float4 w1 = *(const float4*)(ex + (size_t)i * 8 + 4);
    union { unsigned int u; unsigned short us[2]; } uu;
    uu.u = *(const unsigned int*)(g2 + (size_t)s * 256 + t * 2);
    float v0 = bf2f(uu.us[0]), v1 = bf2f(uu.us[1]);
    acc0[0] += w0.x * v0; acc0[1] += w0.y * v0; acc0[2] += w0.z * v0; acc0[3] += w0.w * v0;
    acc0[4] += w1.x * v0; acc0[5] += w1.y * v0; acc0[6] += w1.z * v0; acc0[7] += w1.w * v0;
    acc1[0] += w0.x * v1; acc1[1] += w0.y * v1; acc1[2] += w0.z * v1; acc1[3] += w0.w * v1;
    acc1[4] += w1.x * v1; acc1[5] += w1.y * v1; acc1[6] += w1.z * v1; acc1[7] += w1.w * v1;
  }
#pragma unroll
  for (int h = 0; h < 8; h++) {
    float inv = invden[dst * 8 + h];
    unsigned int pack = (unsigned int)f2bfu(acc0[h] * inv) |
                        ((unsigned int)f2bfu(acc1[h] * inv) << 16);
    *(unsigned int*)(outA + (size_t)dst * 2048 + h * 256 + t * 2) = pack;
  }
}

extern "C" void kernel_launch(void* const* d_in, const int* in_sizes, int n_in,
                              void* d_out, int out_size, void* d_ws, size_t ws_size,
                              hipStream_t stream) {
  const float* x      = (const float*)d_in[0];
  const int*   ei     = (const int*)d_in[1];
  const float* w_in   = (const float*)d_in[2];
  const float* b_in   = (const float*)d_in[3];
  const float* w_t1   = (const float*)d_in[4];
  const float* b_t1   = (const float*)d_in[5];
  const float* w_t2   = (const float*)d_in[6];
  const float* b_t2   = (const float*)d_in[7];
  const float* w_g1   = (const float*)d_in[8];
  const float* a_src1 = (const float*)d_in[9];
  const float* a_dst1 = (const float*)d_in[10];
  const float* b_g1   = (const float*)d_in[11];
  const float* w_g2   = (const float*)d_in[12];
  const float* a_src2 = (const float*)d_in[13];
  const float* a_dst2 = (const float*)d_in[14];
  const float* b_g2   = (const float*)d_in[15];
  const float* w_g3   = (const float*)d_in[16];
  const float* a_src3 = (const float*)d_in[17];
  const float* a_dst3 = (const float*)d_in[18];
  const float* b_g3   = (const float*)d_in[19];
  const float* w_c1   = (const float*)d_in[20];
  const float* b_c1   = (const float*)d_in[21];
  const float* w_c2   = (const float*)d_in[22];
  const float* b_c2   = (const float*)d_in[23];
  const int M = in_sizes[0] / FIN;  // 20000
  const int E = in_sizes[1] / 2;    // 120000
  (void)n_in; (void)out_size; (void)ws_size;

  char* wsb = (char*)d_ws;
  size_t off = 0;
  auto alloc = [&](size_t bytes) {
    void* p = wsb + off;
    off = (off + bytes + 255) & ~(size_t)255;
    return p;
  };
  typedef __hip_bfloat16 bf;
  bf* xb     = (bf*)alloc((size_t)M * 256 * 2);
  bf* wtin   = (bf*)alloc(256 * 256 * 2);
  bf* wtpair = (bf*)alloc(512 * 256 * 2);
  bf* wtt2   = (bf*)alloc(256 * 256 * 2);
  bf* wtg2   = (bf*)alloc(256 * 256 * 2);
  bf* wtg3s  = (bf*)alloc(256 * 2048 * 2);
  bf* wtc1   = (bf*)alloc(256 * 512 * 2);
  bf* actA   = (bf*)alloc((size_t)M * HID * 2);      // h, later g2
  bf* actB   = (bf*)alloc((size_t)M * HID * 2);      // th, later g1
  bf* hW1    = (bf*)alloc((size_t)M * HID * 2);
  bf* comb   = (bf*)alloc((size_t)M * 2 * HID * 2);  // [g | t]
  bf* hWb    = (bf*)alloc((size_t)M * 2048 * 2);     // agg3 out
  float* as_ = (float*)alloc((size_t)M * 8 * 4);
  float* ad_ = (float*)alloc((size_t)M * 8 * 4);
  float* apj = (float*)alloc(256 * 16 * 4);
  float* exw = (float*)alloc((size_t)(E + M) * 8 * 4);
  float* ivd = (float*)alloc((size_t)M * 8 * 4);
  int* degfill = (int*)alloc((size_t)2 * M * 4);
  int* deg   = degfill;
  int* fillc = degfill + M;
  int* rp    = (int*)alloc((size_t)(M + 1) * 4);
  int* colA  = (int*)alloc((size_t)(E + M) * 4);

  // ---- conversions (batched) ----
  xcvt_k<<<(M * 256 + 255) / 256, 256, 0, stream>>>(x, xb, M);
  wprep_k<<<dim3(8, 16, 14), dim3(32, 8), 0, stream>>>(
      w_in, w_t1, w_g1, w_t2, w_g2, w_c1, w_g3, wtin, wtpair, wtt2, wtg2, wtc1, wtg3s);
  aproj_k<<<16, 256, 0, stream>>>(w_g3, a_src3, a_dst3, apj);

  // ---- CSR build ----
  hipMemsetAsync(degfill, 0, (size_t)2 * M * 4, stream);
  count_k<<<(E + 255) / 256, 256, 0, stream>>>(ei, deg, E);
  scan_k<<<1, 1024, 0, stream>>>(deg, rp, M);
  fill_k<<<(E + M + 255) / 256, 256, 0, stream>>>(ei, rp, fillc, colA, E, M);

  int eg = (M + 3) / 4;
  int mg = (M + 63) / 64;

  // h = elu(x @ w_in + b_in) -> actA
  mgemm64_k<2><<<dim3(4, mg), 256, 0, stream>>>(xb, wtin, b_in, actA, HID, M, HID, 256);
  // dual: th=relu(h@w_t1+b_t1) -> actB ; hW1 = h@w_g1
  mgemm_dual_k<<<dim3(4, mg), 256, 0, stream>>>(actA, wtpair, b_t1, actB, hW1, M);
  // t = th @ w_t2 + b_t2 -> comb[:,256:512]
  mgemm64_k<0><<<dim3(4, mg), 256, 0, stream>>>(actB, wtt2, b_t2, comb + HID, 2 * HID, M, HID, 256);

  // ---- GAT 1 ----
  alpha_small_k<<<(M * 8 + 255) / 256, 256, 0, stream>>>(hW1, a_src1, a_dst1, as_, ad_, M);
  aggf_k<<<eg, 256, 0, stream>>>(rp, colA, hW1, as_, ad_, b_g1, actB, M);  // g1

  // ---- GAT 2 ----
  mgemm64_k<0><<<dim3(4, mg), 256, 0, stream>>>(actB, wtg2, nullptr, hW1, HID, M, HID, 256);
  alpha_small_k<<<(M * 8 + 255) / 256, 256, 0, stream>>>(hW1, a_src2, a_dst2, as_, ad_, M);
  aggf_k<<<eg, 256, 0, stream>>>(rp, colA, hW1, as_, ad_, b_g2, actA, M);  // g2

  // ---- GAT 3 ----
  alpha3_k<<<(M + 15) / 16, 256, 0, stream>>>(actA, apj, as_, ad_, M);
  esoft_k<<<eg, 256, 0, stream>>>(rp, colA, as_, ad_, exw, ivd, M);
  agg3_k<<<(M + 1) / 2, 256, 0, stream>>>(rp, colA, actA, exw, ivd, hWb, M);
  mgemm3_k<<<dim3(4, mg), 256, 0, stream>>>(hWb, wtg3s, b_g3, comb, M);

  // ---- classifier (fused logits) ----
  initout_k<<<(M * 2 + 255) / 256, 256, 0, stream>>>(b_c2, (float*)d_out, M);
  mgemm_cls_k<<<dim3(4, mg), 256, 0, stream>>>(comb, wtc1, b_c1, w_c2, (float*)d_out, M);
}

// Round 7
// 435.699 us; speedup vs baseline: 1.2675x; 1.0250x over previous
//
#include <hip/hip_runtime.h>
#include <hip/hip_bf16.h>
#include <math.h>

// CHRONOS inference. Round 7: mgemm3 and classifier as 64x256-tile 512-thread
// kernels (A read once -> FETCH 161->~90MB; latency hidden by 8 waves/block);
// classifier emits logits in-block (no atomics/initout); vectorized alpha/agg3
// tail; aproj folded into wprep.

#define HID 256
#define HEADS 8
#define FIN 235

typedef __attribute__((ext_vector_type(8))) short short8;
typedef __attribute__((ext_vector_type(4))) float floatx4;

__device__ __forceinline__ float elu_f(float x) { return x > 0.f ? x : __expf(x) - 1.f; }
__device__ __forceinline__ float bf2f(unsigned short u) {
  return __uint_as_float(((unsigned int)u) << 16);
}
__device__ __forceinline__ unsigned short f2bfu(float f) {
  union { __hip_bfloat16 b; unsigned short u; } c;
  c.b = __float2bfloat16(f);
  return c.u;
}

// ---------------- conversions ----------------
__global__ void xcvt_k(const float* __restrict__ x, __hip_bfloat16* __restrict__ xb, int M) {
  int id = blockIdx.x * blockDim.x + threadIdx.x;
  if (id >= M * 256) return;
  int m = id >> 8, k = id & 255;
  xb[id] = (k < FIN) ? __float2bfloat16(x[(size_t)m * FIN + k]) : __float2bfloat16(0.f);
}

// batched weight transpose+cast (+ aproj at z=14)
// z: 0=w_in 1=w_t1 2=w_g1 3=w_t2 4=w_g2 5=w_c1 6..13=w_g3 head 14=aproj
__global__ void wprep_k(const float* __restrict__ w_in, const float* __restrict__ w_t1,
                        const float* __restrict__ w_g1, const float* __restrict__ w_t2,
                        const float* __restrict__ w_g2, const float* __restrict__ w_c1,
                        const float* __restrict__ w_g3, const float* __restrict__ a_s3,
                        const float* __restrict__ a_d3, __hip_bfloat16* __restrict__ wtin,
                        __hip_bfloat16* __restrict__ wtpair, __hip_bfloat16* __restrict__ wtt2,
                        __hip_bfloat16* __restrict__ wtg2, __hip_bfloat16* __restrict__ wtc1,
                        __hip_bfloat16* __restrict__ wtg3s, float* __restrict__ apj) {
  __shared__ float t[32][33];
  int z = blockIdx.z;
  if (z == 14) {
    // apj[k*16 + h*2 + sd] = sum_c w_g3[k, h*256+c] * a3_{src|dst}[h,c]
    int idx = (blockIdx.y * 8 + blockIdx.x) * 256 + threadIdx.y * 32 + threadIdx.x;
    if (idx < 256 * 16) {
      int k = idx >> 4, o = idx & 15;
      int h = o >> 1;
      const float* av = (o & 1) ? (a_d3 + h * 256) : (a_s3 + h * 256);
      const float* wr = w_g3 + (size_t)k * 2048 + h * 256;
      float s = 0.f;
      for (int c = 0; c < 256; c++) s += wr[c] * av[c];
      apj[idx] = s;
    }
    return;
  }
  const float* src;
  __hip_bfloat16* dst;
  int K, Kpad, Nstride;
  if (z == 5) {
    src = w_c1; dst = wtc1; K = 512; Kpad = 512; Nstride = 256;
  } else {
    if (blockIdx.y >= 8) return;
    switch (z) {
      case 0: src = w_in; dst = wtin; K = FIN; Kpad = 256; Nstride = 256; break;
      case 1: src = w_t1; dst = wtpair; K = 256; Kpad = 256; Nstride = 256; break;
      case 2: src = w_g1; dst = wtpair + 256 * 256; K = 256; Kpad = 256; Nstride = 256; break;
      case 3: src = w_t2; dst = wtt2; K = 256; Kpad = 256; Nstride = 256; break;
      case 4: src = w_g2; dst = wtg2; K = 256; Kpad = 256; Nstride = 256; break;
      default: {
        int h = z - 6;
        src = w_g3 + h * 256; dst = wtg3s + h * 256; K = 256; Kpad = 2048; Nstride = 2048;
      }
    }
  }
  int nb = blockIdx.x * 32, kb = blockIdx.y * 32;
  int tx = threadIdx.x, ty = threadIdx.y;
#pragma unroll
  for (int j = 0; j < 32; j += 8) {
    int k = kb + ty + j;
    t[ty + j][tx] = (k < K) ? src[(size_t)k * Nstride + nb + tx] : 0.f;
  }
  __syncthreads();
#pragma unroll
  for (int j = 0; j < 32; j += 8) {
    int n = nb + ty + j;
    int k = kb + tx;
    dst[(size_t)n * Kpad + k] = __float2bfloat16(t[tx][ty + j]);
  }
}

// ---------------- CSR build ----------------
__global__ void count_k(const int* __restrict__ ei, int* __restrict__ deg, int E) {
  int i = blockIdx.x * blockDim.x + threadIdx.x;
  if (i < E) atomicAdd(&deg[ei[E + i]], 1);
}

__global__ void scan_k(const int* __restrict__ deg, int* __restrict__ rp, int n) {
  __shared__ int wsum[16];
  __shared__ int s_carry;
  int tid = threadIdx.x, lane = tid & 63, wid = tid >> 6;
  if (tid == 0) { s_carry = 0; rp[0] = 0; }
  __syncthreads();
  for (int base = 0; base < n; base += 1024) {
    int i = base + tid;
    int x = (i < n) ? (deg[i] + 1) : 0;  // +1 self-loop
#pragma unroll
    for (int off = 1; off < 64; off <<= 1) {
      int y = __shfl_up(x, off);
      if (lane >= off) x += y;
    }
    if (lane == 63) wsum[wid] = x;
    __syncthreads();
    if (wid == 0 && lane < 16) {
      int s = wsum[lane];
#pragma unroll
      for (int off = 1; off < 16; off <<= 1) {
        int y = __shfl_up(s, off);
        if (lane >= off) s += y;
      }
      wsum[lane] = s;
    }
    __syncthreads();
    int offset = s_carry + (wid > 0 ? wsum[wid - 1] : 0);
    if (i < n) rp[i + 1] = offset + x;
    __syncthreads();
    if (tid == 1023) s_carry += wsum[15];
    __syncthreads();
  }
}

__global__ void fill_k(const int* __restrict__ ei, const int* __restrict__ rp,
                       int* __restrict__ fillc, int* __restrict__ colA, int E, int n) {
  int i = blockIdx.x * blockDim.x + threadIdx.x;
  if (i < E) {
    int d = ei[E + i];
    int pos = rp[d] + atomicAdd(&fillc[d], 1);
    colA[pos] = ei[i];
  } else if (i < E + n) {
    int v = i - E;
    int pos = rp[v] + atomicAdd(&fillc[v], 1);
    colA[pos] = v;
  }
}

// ---------------- bf16 MFMA GEMM, TILE 64x64, BK=32 ----------------
template <int ACT>
__global__ __launch_bounds__(256) void mgemm64_k(
    const __hip_bfloat16* __restrict__ A, const __hip_bfloat16* __restrict__ Bt,
    const float* __restrict__ bias, __hip_bfloat16* __restrict__ Cb,
    int ldc, int M, int N, int K) {
  __shared__ short As[64 * 40];
  __shared__ short Bs[64 * 40];
  int tid = threadIdx.x;
  int row0 = blockIdx.y * 64, col0 = blockIdx.x * 64;
  int w = tid >> 6, lane = tid & 63;
  int wr = w >> 1, wc = w & 1;
  int quad = lane >> 4, l16 = lane & 15;
  floatx4 zero = {0.f, 0.f, 0.f, 0.f};
  floatx4 acc[2][2];
#pragma unroll
  for (int i = 0; i < 2; i++)
#pragma unroll
    for (int j = 0; j < 2; j++) acc[i][j] = zero;

  int srow = tid >> 2, sq = tid & 3;
  const __hip_bfloat16* Ap = A + (size_t)(row0 + srow) * K + sq * 8;
  const __hip_bfloat16* Bp = Bt + (size_t)(col0 + srow) * K + sq * 8;
  bool aok = (row0 + srow) < M;

  uint4 a1 = make_uint4(0, 0, 0, 0);
  if (aok) a1 = *(const uint4*)(Ap);
  uint4 b1 = *(const uint4*)(Bp);

  for (int k0 = 0; k0 < K; k0 += 32) {
    __syncthreads();
    *(uint4*)&As[srow * 40 + sq * 8] = a1;
    *(uint4*)&Bs[srow * 40 + sq * 8] = b1;
    int kn = k0 + 32;
    if (kn < K) {
      if (aok) a1 = *(const uint4*)(Ap + kn);
      b1 = *(const uint4*)(Bp + kn);
    }
    __syncthreads();
    short8 fa[2], fb[2];
#pragma unroll
    for (int i = 0; i < 2; i++) {
      fa[i] = *(const short8*)&As[(wr * 32 + i * 16 + l16) * 40 + quad * 8];
      fb[i] = *(const short8*)&Bs[(wc * 32 + i * 16 + l16) * 40 + quad * 8];
    }
#pragma unroll
    for (int mi = 0; mi < 2; mi++)
#pragma unroll
      for (int ni = 0; ni < 2; ni++)
        acc[mi][ni] = __builtin_amdgcn_mfma_f32_16x16x32_bf16(fa[mi], fb[ni], acc[mi][ni], 0, 0, 0);
  }

#pragma unroll
  for (int mi = 0; mi < 2; mi++) {
    int rbase = row0 + wr * 32 + mi * 16 + quad * 4;
#pragma unroll
    for (int ni = 0; ni < 2; ni++) {
      int c = col0 + wc * 32 + ni * 16 + l16;
      float bv = bias ? bias[c] : 0.f;
#pragma unroll
      for (int reg = 0; reg < 4; reg++) {
        int rr = rbase + reg;
        if (rr >= M) continue;
        float v = acc[mi][ni][reg] + bv;
        if (ACT == 1) v = fmaxf(v, 0.f);
        if (ACT == 2) v = elu_f(v);
        Cb[(size_t)rr * ldc + c] = __float2bfloat16(v);
      }
    }
  }
}

// ---------------- dual GEMM (N=512): A@[w_t1 | w_g1], split epilogue ----------------
__global__ __launch_bounds__(256) void mgemm_dual_k(
    const __hip_bfloat16* __restrict__ A, const __hip_bfloat16* __restrict__ Bt,
    const float* __restrict__ bias1, __hip_bfloat16* __restrict__ O1,
    __hip_bfloat16* __restrict__ O2, int M) {
  const int K = 256;
  __shared__ short As[64 * 40];
  __shared__ short Bs[128 * 40];
  int tid = threadIdx.x;
  int row0 = blockIdx.y * 64, col0 = blockIdx.x * 128;
  int w = tid >> 6, lane = tid & 63;
  int wr = w >> 1, wc = w & 1;
  int quad = lane >> 4, l16 = lane & 15;
  floatx4 zero = {0.f, 0.f, 0.f, 0.f};
  floatx4 acc[2][4];
#pragma unroll
  for (int i = 0; i < 2; i++)
#pragma unroll
    for (int j = 0; j < 4; j++) acc[i][j] = zero;

  int srow = tid >> 2, sq = tid & 3;
  const __hip_bfloat16* Ap = A + (size_t)(row0 + srow) * K + sq * 8;
  const __hip_bfloat16* Bp1 = Bt + (size_t)(col0 + srow) * K + sq * 8;
  const __hip_bfloat16* Bp2 = Bt + (size_t)(col0 + 64 + srow) * K + sq * 8;
  bool aok = (row0 + srow) < M;

  uint4 a1 = make_uint4(0, 0, 0, 0);
  if (aok) a1 = *(const uint4*)(Ap);
  uint4 b1 = *(const uint4*)(Bp1);
  uint4 b2 = *(const uint4*)(Bp2);

  for (int k0 = 0; k0 < K; k0 += 32) {
    __syncthreads();
    *(uint4*)&As[srow * 40 + sq * 8] = a1;
    *(uint4*)&Bs[srow * 40 + sq * 8] = b1;
    *(uint4*)&Bs[(64 + srow) * 40 + sq * 8] = b2;
    int kn = k0 + 32;
    if (kn < K) {
      if (aok) a1 = *(const uint4*)(Ap + kn);
      b1 = *(const uint4*)(Bp1 + kn);
      b2 = *(const uint4*)(Bp2 + kn);
    }
    __syncthreads();
    short8 fa[2], fb[4];
#pragma unroll
    for (int i = 0; i < 2; i++)
      fa[i] = *(const short8*)&As[(wr * 32 + i * 16 + l16) * 40 + quad * 8];
#pragma unroll
    for (int i = 0; i < 4; i++)
      fb[i] = *(const short8*)&Bs[(wc * 64 + i * 16 + l16) * 40 + quad * 8];
#pragma unroll
    for (int mi = 0; mi < 2; mi++)
#pragma unroll
      for (int ni = 0; ni < 4; ni++)
        acc[mi][ni] = __builtin_amdgcn_mfma_f32_16x16x32_bf16(fa[mi], fb[ni], acc[mi][ni], 0, 0, 0);
  }

#pragma unroll
  for (int mi = 0; mi < 2; mi++) {
    int rbase = row0 + wr * 32 + mi * 16 + quad * 4;
#pragma unroll
    for (int ni = 0; ni < 4; ni++) {
      int c = col0 + wc * 64 + ni * 16 + l16;
      bool first = c < 256;
      float bv = first ? bias1[c] : 0.f;
      int cc = first ? c : (c - 256);
#pragma unroll
      for (int reg = 0; reg < 4; reg++) {
        int rr = rbase + reg;
        if (rr >= M) continue;
        float v = acc[mi][ni][reg] + bv;
        if (first) v = fmaxf(v, 0.f);
        __hip_bfloat16* dst = first ? O1 : O2;
        dst[(size_t)rr * 256 + cc] = __float2bfloat16(v);
      }
    }
  }
}

// ---------------- GAT3 GEMM: 64x256 tile, 512 threads, A read once ----------------
// A [M,2048], Bt [256,2048]. 8 waves: wr=w&3 (16 rows), wc=w>>2 (128 cols).
// Fold elu(acc + b_h) every 256 k; comb[:,0:256] = 0.125 * sum_h.
__global__ __launch_bounds__(512) void mgemm3_k(
    const __hip_bfloat16* __restrict__ A, const __hip_bfloat16* __restrict__ Bt,
    const float* __restrict__ bias, __hip_bfloat16* __restrict__ comb, int M) {
  const int K = 2048;
  __shared__ short As[64 * 40];
  __shared__ short Bs[256 * 40];
  int tid = threadIdx.x;
  int row0 = blockIdx.x * 64;
  int w = tid >> 6, lane = tid & 63;
  int wr = w & 3, wc = w >> 2;
  int quad = lane >> 4, l16 = lane & 15;
  floatx4 acc[8], sum[8];
#pragma unroll
  for (int i = 0; i < 8; i++) {
    acc[i] = (floatx4){0.f, 0.f, 0.f, 0.f};
    sum[i] = (floatx4){0.f, 0.f, 0.f, 0.f};
  }

  bool at = tid < 256;
  int arow = tid >> 2, achk = (tid & 3) * 8;
  const __hip_bfloat16* Ap = A + (size_t)(row0 + arow) * K + achk;
  bool aok = at && (row0 + arow) < M;
  int brow = tid >> 1, boff = (tid & 1) * 16;
  const __hip_bfloat16* Bp = Bt + (size_t)brow * K + boff;

  uint4 a1 = make_uint4(0, 0, 0, 0);
  if (aok) a1 = *(const uint4*)(Ap);
  uint4 b1 = *(const uint4*)(Bp);
  uint4 b2 = *(const uint4*)(Bp + 8);

  for (int k0 = 0; k0 < K; k0 += 32) {
    __syncthreads();
    if (at) *(uint4*)&As[arow * 40 + achk] = a1;
    *(uint4*)&Bs[brow * 40 + boff] = b1;
    *(uint4*)&Bs[brow * 40 + boff + 8] = b2;
    int kn = k0 + 32;
    if (kn < K) {
      if (aok) a1 = *(const uint4*)(Ap + kn);
      b1 = *(const uint4*)(Bp + kn);
      b2 = *(const uint4*)(Bp + kn + 8);
    }
    __syncthreads();
    short8 fa = *(const short8*)&As[(wr * 16 + l16) * 40 + quad * 8];
#pragma unroll
    for (int ni = 0; ni < 8; ni++) {
      short8 fb = *(const short8*)&Bs[(wc * 128 + ni * 16 + l16) * 40 + quad * 8];
      acc[ni] = __builtin_amdgcn_mfma_f32_16x16x32_bf16(fa, fb, acc[ni], 0, 0, 0);
    }
    if (((k0 + 32) & 255) == 0) {
      int h = k0 >> 8;
#pragma unroll
      for (int ni = 0; ni < 8; ni++) {
        int c = wc * 128 + ni * 16 + l16;
        float bv = bias[h * 256 + c];
#pragma unroll
        for (int reg = 0; reg < 4; reg++) {
          sum[ni][reg] += elu_f(acc[ni][reg] + bv);
          acc[ni][reg] = 0.f;
        }
      }
    }
  }

  int rbase = row0 + wr * 16 + quad * 4;
#pragma unroll
  for (int ni = 0; ni < 8; ni++) {
    int c = wc * 128 + ni * 16 + l16;
#pragma unroll
    for (int reg = 0; reg < 4; reg++) {
      int rr = rbase + reg;
      if (rr >= M) continue;
      comb[(size_t)rr * 512 + c] = __float2bfloat16(sum[ni][reg] * 0.125f);
    }
  }
}

// ---------------- classifier: 64x256 tile, 512 threads, fused logits ----------------
// hidden = relu(comb @ w_c1 + b_c1) in regs; logits = hidden @ w_c2 + b_c2,
// reduced via shfl+LDS, written directly (block covers full K and N).
__global__ __launch_bounds__(512) void mgemm_cls_k(
    const __hip_bfloat16* __restrict__ A, const __hip_bfloat16* __restrict__ Bt,
    const float* __restrict__ bias, const float* __restrict__ w2,
    const float* __restrict__ b2f, float* __restrict__ out, int M) {
  const int K = 512;
  __shared__ short As[64 * 40];
  __shared__ short Bs[256 * 40];
  __shared__ float ls[64][2][2];
  int tid = threadIdx.x;
  int row0 = blockIdx.x * 64;
  int w = tid >> 6, lane = tid & 63;
  int wr = w & 3, wc = w >> 2;
  int quad = lane >> 4, l16 = lane & 15;
  floatx4 acc[8];
#pragma unroll
  for (int i = 0; i < 8; i++) acc[i] = (floatx4){0.f, 0.f, 0.f, 0.f};

  bool at = tid < 256;
  int arow = tid >> 2, achk = (tid & 3) * 8;
  const __hip_bfloat16* Ap = A + (size_t)(row0 + arow) * K + achk;
  bool aok = at && (row0 + arow) < M;
  int brow = tid >> 1, boff = (tid & 1) * 16;
  const __hip_bfloat16* Bp = Bt + (size_t)brow * K + boff;

  uint4 a1 = make_uint4(0, 0, 0, 0);
  if (aok) a1 = *(const uint4*)(Ap);
  uint4 b1 = *(const uint4*)(Bp);
  uint4 b2 = *(const uint4*)(Bp + 8);

  for (int k0 = 0; k0 < K; k0 += 32) {
    __syncthreads();
    if (at) *(uint4*)&As[arow * 40 + achk] = a1;
    *(uint4*)&Bs[brow * 40 + boff] = b1;
    *(uint4*)&Bs[brow * 40 + boff + 8] = b2;
    int kn = k0 + 32;
    if (kn < K) {
      if (aok) a1 = *(const uint4*)(Ap + kn);
      b1 = *(const uint4*)(Bp + kn);
      b2 = *(const uint4*)(Bp + kn + 8);
    }
    __syncthreads();
    short8 fa = *(const short8*)&As[(wr * 16 + l16) * 40 + quad * 8];
#pragma unroll
    for (int ni = 0; ni < 8; ni++) {
      short8 fb = *(const short8*)&Bs[(wc * 128 + ni * 16 + l16) * 40 + quad * 8];
      acc[ni] = __builtin_amdgcn_mfma_f32_16x16x32_bf16(fa, fb, acc[ni], 0, 0, 0);
    }
  }

  float p0[4] = {0.f, 0.f, 0.f, 0.f}, p1[4] = {0.f, 0.f, 0.f, 0.f};
#pragma unroll
  for (int ni = 0; ni < 8; ni++) {
    int c = wc * 128 + ni * 16 + l16;
    float bv = bias[c];
    float w20 = w2[c * 2 + 0], w21 = w2[c * 2 + 1];
#pragma unroll
    for (int reg = 0; reg < 4; reg++) {
      float v = fmaxf(acc[ni][reg] + bv, 0.f);
      p0[reg] += v * w20;
      p1[reg] += v * w21;
    }
  }
#pragma unroll
  for (int off = 1; off < 16; off <<= 1)
#pragma unroll
    for (int reg = 0; reg < 4; reg++) {
      p0[reg] += __shfl_xor(p0[reg], off);
      p1[reg] += __shfl_xor(p1[reg], off);
    }
  if (l16 == 0) {
#pragma unroll
    for (int reg = 0; reg < 4; reg++) {
      int rl = wr * 16 + quad * 4 + reg;
      ls[rl][wc][0] = p0[reg];
      ls[rl][wc][1] = p1[reg];
    }
  }
  __syncthreads();
  if (tid < 64) {
    int r = row0 + tid;
    if (r < M) {
      out[r * 2 + 0] = ls[tid][0][0] + ls[tid][1][0] + b2f[0];
      out[r * 2 + 1] = ls[tid][0][1] + ls[tid][1][1] + b2f[1];
    }
  }
}

// ---------------- alpha3: apj in LDS, vectorized row loads ----------------
__global__ __launch_bounds__(256) void alpha3_k(const __hip_bfloat16* __restrict__ g2,
                                                const float* __restrict__ apj,
                                                float* __restrict__ as_, float* __restrict__ ad_,
                                                int M) {
  __shared__ float sapj[4096];
  int tid = threadIdx.x;
  for (int i = tid; i < 4096; i += 256) sapj[i] = apj[i];
  __syncthreads();
  int nl = tid >> 4, o = tid & 15;
  int n = blockIdx.x * 16 + nl;
  if (n >= M) return;
  const __hip_bfloat16* row = g2 + (size_t)n * 256;
  float s = 0.f;
  for (int cc = 0; cc < 256; cc += 8) {
    short8 v8 = *(const short8*)(row + cc);
#pragma unroll
    for (int j = 0; j < 8; j++)
      s += bf2f((unsigned short)v8[j]) * sapj[(cc + j) * 16 + o];
  }
  if (o & 1) ad_[n * 8 + (o >> 1)] = s;
  else as_[n * 8 + (o >> 1)] = s;
}

// ---------------- alpha (layers 1/2), uint4-vectorized ----------------
__global__ void alpha_small_k(const __hip_bfloat16* __restrict__ hW, const float* __restrict__ a_s,
                              const float* __restrict__ a_d, float* __restrict__ as_,
                              float* __restrict__ ad_, int M) {
  int idx = blockIdx.x * blockDim.x + threadIdx.x;
  if (idx >= M * HEADS) return;
  int h = idx & 7;
  const __hip_bfloat16* row = hW + (size_t)(idx >> 3) * HID + h * 32;
  const float* ws = a_s + h * 32;
  const float* wd = a_d + h * 32;
  float s = 0.f, d = 0.f;
#pragma unroll
  for (int cc = 0; cc < 32; cc += 8) {
    short8 v8 = *(const short8*)(row + cc);
#pragma unroll
    for (int j = 0; j < 8; j++) {
      float v = bf2f((unsigned short)v8[j]);
      s += v * ws[cc + j];
      d += v * wd[cc + j];
    }
  }
  as_[idx] = s;
  ad_[idx] = d;
}

// ---------------- fused edge-softmax + aggregate (GAT1/2), wave per dst ----------------
__global__ __launch_bounds__(256) void aggf_k(const int* __restrict__ rp,
                                              const int* __restrict__ col,
                                              const __hip_bfloat16* __restrict__ hW,
                                              const float* __restrict__ as_,
                                              const float* __restrict__ ad_,
                                              const float* __restrict__ bias,
                                              __hip_bfloat16* __restrict__ out, int M) {
  int dst = blockIdx.x * 4 + (threadIdx.x >> 6);
  if (dst >= M) return;
  int t = threadIdx.x & 63;
  int h = t >> 3, c = t << 2;
  int beg = rp[dst], end = rp[dst + 1];
  float adv = ad_[dst * 8 + h];
  float m = -3.4e38f;
  for (int i = beg; i < end; i++) {
    float e = as_[col[i] * 8 + h] + adv;
    e = e > 0.f ? e : 0.2f * e;
    m = fmaxf(m, e);
  }
  float den = 0.f;
  float a0 = 0.f, a1 = 0.f, a2 = 0.f, a3 = 0.f;
  for (int i = beg; i < end; i++) {
    int s = col[i];
    float e = as_[s * 8 + h] + adv;
    e = e > 0.f ? e : 0.2f * e;
    float ex = __expf(e - m);
    den += ex;
    union { uint2 u; unsigned short us[4]; } uu;
    uu.u = *(const uint2*)(hW + (size_t)s * HID + c);
    a0 += ex * bf2f(uu.us[0]);
    a1 += ex * bf2f(uu.us[1]);
    a2 += ex * bf2f(uu.us[2]);
    a3 += ex * bf2f(uu.us[3]);
  }
  float inv = 1.f / (den + 1e-16f);
  out[(size_t)dst * HID + c + 0] = __float2bfloat16(elu_f(a0 * inv + bias[c + 0]));
  out[(size_t)dst * HID + c + 1] = __float2bfloat16(elu_f(a1 * inv + bias[c + 1]));
  out[(size_t)dst * HID + c + 2] = __float2bfloat16(elu_f(a2 * inv + bias[c + 2]));
  out[(size_t)dst * HID + c + 3] = __float2bfloat16(elu_f(a3 * inv + bias[c + 3]));
}

// ---------------- edge softmax (GAT3) ----------------
__global__ __launch_bounds__(256) void esoft_k(const int* __restrict__ rp,
                                               const int* __restrict__ col,
                                               const float* __restrict__ as_,
                                               const float* __restrict__ ad_,
                                               float* __restrict__ ex,
                                               float* __restrict__ invden, int M) {
  int dst = blockIdx.x * 4 + (threadIdx.x >> 6);
  if (dst >= M) return;
  int lane = threadIdx.x & 63;
  int es = lane >> 3, h = lane & 7;
  int beg = rp[dst], end = rp[dst + 1];
  float adv = ad_[dst * 8 + h];
  float m = -3.4e38f;
  for (int i = beg + es; i < end; i += 8) {
    float e = as_[col[i] * 8 + h] + adv;
    e = e > 0.f ? e : 0.2f * e;
    m = fmaxf(m, e);
  }
  m = fmaxf(m, __shfl_xor(m, 8));
  m = fmaxf(m, __shfl_xor(m, 16));
  m = fmaxf(m, __shfl_xor(m, 32));
  float den = 0.f;
  for (int i = beg + es; i < end; i += 8) {
    float e = as_[col[i] * 8 + h] + adv;
    e = e > 0.f ? e : 0.2f * e;
    float v = __expf(e - m);
    ex[(size_t)i * 8 + h] = v;
    den += v;
  }
  den += __shfl_xor(den, 8);
  den += __shfl_xor(den, 16);
  den += __shfl_xor(den, 32);
  if (es == 0) invden[dst * 8 + h] = 1.f / (den + 1e-16f);
}

// ---------------- GAT3 aggregate: 4 dsts/block, 64 thr/dst, uint2 ----------------
__global__ __launch_bounds__(256) void agg3_k(const int* __restrict__ rp,
                                              const int* __restrict__ col,
                                              const __hip_bfloat16* __restrict__ g2,
                                              const float* __restrict__ ex,
                                              const float* __restrict__ invden,
                                              __hip_bfloat16* __restrict__ outA, int M) {
  int dst = blockIdx.x * 4 + (threadIdx.x >> 6);
  if (dst >= M) return;
  int t = threadIdx.x & 63;  // channels 4t..4t+3
  int beg = rp[dst], end = rp[dst + 1];
  float acc[4][8];
#pragma unroll
  for (int ch = 0; ch < 4; ch++)
#pragma unroll
    for (int h = 0; h < 8; h++) acc[ch][h] = 0.f;
  for (int i = beg; i < end; i++) {
    int s = col[i];
    float4 w0 = *(const float4*)(ex + (size_t)i * 8);
    float4 w1 = *(const float4*)(ex + (size_t)i * 8 + 4);
    union { uint2 u; unsigned short us[4]; } uu;
    uu.u = *(const uint2*)(g2 + (size_t)s * 256 + t * 4);
#pragma unroll
    for (int ch = 0; ch < 4; ch++) {
      float v = bf2f(uu.us[ch]);
      acc[ch][0] += w0.x * v; acc[ch][1] += w0.y * v;
      acc[ch][2] += w0.z * v; acc[ch][3] += w0.w * v;
      acc[ch][4] += w1.x * v; acc[ch][5] += w1.y * v;
      acc[ch][6] += w1.z * v; acc[ch][7] += w1.w * v;
    }
  }
#pragma unroll
  for (int h = 0; h < 8; h++) {
    float inv = invden[dst * 8 + h];
    union { uint2 u; unsigned short us[4]; } pk;
#pragma unroll
    for (int ch = 0; ch < 4; ch++) pk.us[ch] = f2bfu(acc[ch][h] * inv);
    *(uint2*)(outA + (size_t)dst * 2048 + h * 256 + t * 4) = pk.u;
  }
}

extern "C" void kernel_launch(void* const* d_in, const int* in_sizes, int n_in,
                              void* d_out, int out_size, void* d_ws, size_t ws_size,
                              hipStream_t stream) {
  const float* x      = (const float*)d_in[0];
  const int*   ei     = (const int*)d_in[1];
  const float* w_in   = (const float*)d_in[2];
  const float* b_in   = (const float*)d_in[3];
  const float* w_t1   = (const float*)d_in[4];
  const float* b_t1   = (const float*)d_in[5];
  const float* w_t2   = (const float*)d_in[6];
  const float* b_t2   = (const float*)d_in[7];
  const float* w_g1   = (const float*)d_in[8];
  const float* a_src1 = (const float*)d_in[9];
  const float* a_dst1 = (const float*)d_in[10];
  const float* b_g1   = (const float*)d_in[11];
  const float* w_g2   = (const float*)d_in[12];
  const float* a_src2 = (const float*)d_in[13];
  const float* a_dst2 = (const float*)d_in[14];
  const float* b_g2   = (const float*)d_in[15];
  const float* w_g3   = (const float*)d_in[16];
  const float* a_src3 = (const float*)d_in[17];
  const float* a_dst3 = (const float*)d_in[18];
  const float* b_g3   = (const float*)d_in[19];
  const float* w_c1   = (const float*)d_in[20];
  const float* b_c1   = (const float*)d_in[21];
  const float* w_c2   = (const float*)d_in[22];
  const float* b_c2   = (const float*)d_in[23];
  const int M = in_sizes[0] / FIN;  // 20000
  const int E = in_sizes[1] / 2;    // 120000
  (void)n_in; (void)out_size; (void)ws_size;

  char* wsb = (char*)d_ws;
  size_t off = 0;
  auto alloc = [&](size_t bytes) {
    void* p = wsb + off;
    off = (off + bytes + 255) & ~(size_t)255;
    return p;
  };
  typedef __hip_bfloat16 bf;
  bf* xb     = (bf*)alloc((size_t)M * 256 * 2);
  bf* wtin   = (bf*)alloc(256 * 256 * 2);
  bf* wtpair = (bf*)alloc(512 * 256 * 2);
  bf* wtt2   = (bf*)alloc(256 * 256 * 2);
  bf* wtg2   = (bf*)alloc(256 * 256 * 2);
  bf* wtg3s  = (bf*)alloc(256 * 2048 * 2);
  bf* wtc1   = (bf*)alloc(256 * 512 * 2);
  bf* actA   = (bf*)alloc((size_t)M * HID * 2);      // h, later g2
  bf* actB   = (bf*)alloc((size_t)M * HID * 2);      // th, later g1
  bf* hW1    = (bf*)alloc((size_t)M * HID * 2);
  bf* comb   = (bf*)alloc((size_t)M * 2 * HID * 2);  // [g | t]
  bf* hWb    = (bf*)alloc((size_t)M * 2048 * 2);     // agg3 out
  float* as_ = (float*)alloc((size_t)M * 8 * 4);
  float* ad_ = (float*)alloc((size_t)M * 8 * 4);
  float* apj = (float*)alloc(256 * 16 * 4);
  float* exw = (float*)alloc((size_t)(E + M) * 8 * 4);
  float* ivd = (float*)alloc((size_t)M * 8 * 4);
  int* degfill = (int*)alloc((size_t)2 * M * 4);
  int* deg   = degfill;
  int* fillc = degfill + M;
  int* rp    = (int*)alloc((size_t)(M + 1) * 4);
  int* colA  = (int*)alloc((size_t)(E + M) * 4);

  // ---- conversions (batched; z=14 computes apj) ----
  xcvt_k<<<(M * 256 + 255) / 256, 256, 0, stream>>>(x, xb, M);
  wprep_k<<<dim3(8, 16, 15), dim3(32, 8), 0, stream>>>(
      w_in, w_t1, w_g1, w_t2, w_g2, w_c1, w_g3, a_src3, a_dst3,
      wtin, wtpair, wtt2, wtg2, wtc1, wtg3s, apj);

  // ---- CSR build ----
  hipMemsetAsync(degfill, 0, (size_t)2 * M * 4, stream);
  count_k<<<(E + 255) / 256, 256, 0, stream>>>(ei, deg, E);
  scan_k<<<1, 1024, 0, stream>>>(deg, rp, M);
  fill_k<<<(E + M + 255) / 256, 256, 0, stream>>>(ei, rp, fillc, colA, E, M);

  int eg = (M + 3) / 4;
  int mg = (M + 63) / 64;

  // h = elu(x @ w_in + b_in) -> actA
  mgemm64_k<2><<<dim3(4, mg), 256, 0, stream>>>(xb, wtin, b_in, actA, HID, M, HID, 256);
  // dual: th=relu(h@w_t1+b_t1) -> actB ; hW1 = h@w_g1
  mgemm_dual_k<<<dim3(4, mg), 256, 0, stream>>>(actA, wtpair, b_t1, actB, hW1, M);
  // t = th @ w_t2 + b_t2 -> comb[:,256:512]
  mgemm64_k<0><<<dim3(4, mg), 256, 0, stream>>>(actB, wtt2, b_t2, comb + HID, 2 * HID, M, HID, 256);

  // ---- GAT 1 ----
  alpha_small_k<<<(M * 8 + 255) / 256, 256, 0, stream>>>(hW1, a_src1, a_dst1, as_, ad_, M);
  aggf_k<<<eg, 256, 0, stream>>>(rp, colA, hW1, as_, ad_, b_g1, actB, M);  // g1

  // ---- GAT 2 ----
  mgemm64_k<0><<<dim3(4, mg), 256, 0, stream>>>(actB, wtg2, nullptr, hW1, HID, M, HID, 256);
  alpha_small_k<<<(M * 8 + 255) / 256, 256, 0, stream>>>(hW1, a_src2, a_dst2, as_, ad_, M);
  aggf_k<<<eg, 256, 0, stream>>>(rp, colA, hW1, as_, ad_, b_g2, actA, M);  // g2

  // ---- GAT 3 ----
  alpha3_k<<<(M + 15) / 16, 256, 0, stream>>>(actA, apj, as_, ad_, M);
  esoft_k<<<eg, 256, 0, stream>>>(rp, colA, as_, ad_, exw, ivd, M);
  agg3_k<<<eg, 256, 0, stream>>>(rp, colA, actA, exw, ivd, hWb, M);
  mgemm3_k<<<mg, 512, 0, stream>>>(hWb, wtg3s, b_g3, comb, M);

  // ---- classifier (direct logits) ----
  mgemm_cls_k<<<mg, 512, 0, stream>>>(comb, wtc1, b_c1, w_c2, b_c2, (float*)d_out, M);
}